// Round 10
// baseline (198.700 us; speedup 1.0000x reference)
//
#include <hip/hip_runtime.h>
#include <hip/hip_fp16.h>

typedef _Float16 f16;
typedef _Float16 f16x8 __attribute__((ext_vector_type(8)));
typedef _Float16 f16x4 __attribute__((ext_vector_type(4)));
typedef float    f32x4 __attribute__((ext_vector_type(4)));
typedef float    f32x16 __attribute__((ext_vector_type(16)));

#define DEV __device__ __forceinline__

DEV int imin(int a, int b) { return a < b ? a : b; }

#if defined(__has_builtin)
#  if __has_builtin(__builtin_amdgcn_exp2f)
#    define EXP2(x) __builtin_amdgcn_exp2f(x)
#  else
#    define EXP2(x) __expf((x) * 0.6931471805599453f)
#  endif
#else
#  define EXP2(x) __expf((x) * 0.6931471805599453f)
#endif

// q pre-scale: (1/sqrt(32)) * log2(e) so softmax is p = 2^s
#define QSCALE (0.17677669529663687f * 1.4426950408889634f)

// ---------------------------------------------------------------------------
// Problem constants: B=16, N=1044, DIM=512, H=8, KD=32, D=64
// q padded to 1152 rows, k/v to 1088, o cols to 1056
// ---------------------------------------------------------------------------

// workspace offsets (bytes) — round-3/6 proven layout
constexpr size_t OFF_XH   = 0;            // x fp16 (16704,512)          17,104,896
constexpr size_t OFF_WQ   = 17104896;     // qkv_w fp16 (1024,512)        1,048,576
constexpr size_t OFF_PW   = 18153472;     // proj_w fp16 (1024,1056)      2,162,688
constexpr size_t OFF_OW   = 20316160;     // out_w fp16 (512,512)           524,288
constexpr size_t OFF_BNA  = 20840448;     // bn scale fp32 (1024)
constexpr size_t OFF_BNB  = 20844544;     // bn shift fp32 (1024)
constexpr size_t OFF_QB   = 20848640;     // q fp16 (128,1152,32)         9,437,184
constexpr size_t OFF_KB   = 30285824;     // k fp16 (128,1088,32)         8,912,896
constexpr size_t OFF_VT   = 39198720;     // v^T fp16 (128,64,1088)      17,825,792
constexpr size_t OFF_OPAD = 57024512;     // o fp16 (16,512,1056)        17,301,504
constexpr size_t OFF_VCT  = 74326016;     // vcT fp16 (16,1024,512)      16,777,216
constexpr size_t OFF_XOT  = 91103232;     // xoT fp16 (16,1024,512)      16,777,216

DEV f32x16 zero16() {
  f32x16 z;
  #pragma unroll
  for (int i = 0; i < 16; ++i) z[i] = 0.f;
  return z;
}

DEV unsigned pk2(float a, float b) {
  auto h = __builtin_amdgcn_cvt_pkrtz(a, b);
  union { decltype(h) x; unsigned u; } t;
  t.x = h;
  return t.u;
}

DEV void plswap(unsigned &a, unsigned &b) {
  asm("v_permlane32_swap_b32 %0, %1" : "+v"(a), "+v"(b));
}

union W4 { unsigned w[4]; f16x8 v; };

DEV void pack_block(const float p[16], f16x8 &a0, f16x8 &a1) {
  unsigned w0 = pk2(p[0], p[1]),   w1 = pk2(p[2], p[3]);
  unsigned w2 = pk2(p[4], p[5]),   w3 = pk2(p[6], p[7]);
  unsigned w4 = pk2(p[8], p[9]),   w5 = pk2(p[10], p[11]);
  unsigned w6 = pk2(p[12], p[13]), w7 = pk2(p[14], p[15]);
  plswap(w0, w2); plswap(w1, w3);
  plswap(w4, w6); plswap(w5, w7);
  W4 u; u.w[0] = w0; u.w[1] = w1; u.w[2] = w2; u.w[3] = w3; a0 = u.v;
  W4 v; v.w[0] = w4; v.w[1] = w5; v.w[2] = w6; v.w[3] = w7; a1 = v.v;
}

// ---------------------------------------------------------------------------
// prep (round-6/8 verbatim)
// ---------------------------------------------------------------------------
__global__ __launch_bounds__(256) void prep_kernel(
    const float* __restrict__ x, const float* __restrict__ qkv_w,
    const float* __restrict__ bn_g, const float* __restrict__ bn_b,
    const float* __restrict__ bn_m, const float* __restrict__ bn_v,
    const float* __restrict__ proj_w, const float* __restrict__ out_w,
    f16* __restrict__ x_h, f16* __restrict__ wq_h, f16* __restrict__ pw_h,
    f16* __restrict__ ow_h, float* __restrict__ bn_a, float* __restrict__ bn_sh,
    f16* __restrict__ qb, f16* __restrict__ kb, f16* __restrict__ vt,
    f16* __restrict__ opad)
{
  long tid = (long)blockIdx.x * blockDim.x + threadIdx.x;
  long gsz = (long)gridDim.x * blockDim.x;

  for (long i = tid; i < 2138112; i += gsz) {
    float4 f = ((const float4*)x)[i];
    f16x4 o = {(f16)f.x, (f16)f.y, (f16)f.z, (f16)f.w};
    ((f16x4*)x_h)[i] = o;
  }
  for (long i = tid; i < 524288; i += gsz) wq_h[i] = (f16)qkv_w[i];
  for (long i = tid; i < 1081344; i += gsz) {
    long m = i / 1056, nn = i - m * 1056;
    pw_h[i] = (nn < 1044) ? (f16)proj_w[m * 1044 + nn] : (f16)0.f;
  }
  for (long i = tid; i < 262144; i += gsz) ow_h[i] = (f16)out_w[i];
  for (long i = tid; i < 1024; i += gsz) {
    float a = bn_g[i] * rsqrtf(bn_v[i] + 1e-5f);
    bn_a[i] = a;
    bn_sh[i] = bn_b[i] - bn_m[i] * a;
  }
  for (long i = tid; i < 13824; i += gsz) {
    int bh = (int)(i / 108);
    int nn = 1044 + (int)(i - (long)bh * 108);
    f16* q = qb + ((long)bh * 1152 + nn) * 32;
    for (int j = 0; j < 32; ++j) q[j] = (f16)0.f;
  }
  for (long i = tid; i < 5632; i += gsz) {
    int bh = (int)(i / 44);
    int nn = 1044 + (int)(i - (long)bh * 44);
    f16* k = kb + ((long)bh * 1088 + nn) * 32;
    for (int j = 0; j < 32; ++j) k[j] = (f16)0.f;
  }
  for (long i = tid; i < 8192; i += gsz) {
    f16* v = vt + i * 1088 + 1044;
    for (int j = 0; j < 44; ++j) v[j] = (f16)0.f;
  }
  for (long i = tid; i < 8192; i += gsz) {
    f16* o = opad + i * 1056 + 1044;
    for (int j = 0; j < 12; ++j) o[j] = (f16)0.f;
  }
}

// ---------------------------------------------------------------------------
// shared 128x128xK NT-GEMM core (round-7/8 proven)
// ---------------------------------------------------------------------------
DEV void gemm_core(const f16* __restrict__ A, const f16* __restrict__ B,
                   int lda, int ldb, int kIters, int rowClampA, int rowClampB,
                   f16* As, f16* Bs, f32x4 acc[4][4])
{
  const int t = threadIdx.x;
  const int wave = t >> 6, lane = t & 63;
  const int wr = wave >> 1, wc = wave & 1;
  const int r0 = t >> 2, seg = t & 3;
  const int fr = lane & 15, fg = lane >> 4;
  const int ra0 = imin(r0, rowClampA);
  const int ra1 = imin(r0 + 64, rowClampA);
  const int rb0 = imin(r0, rowClampB);
  const int rb1 = imin(r0 + 64, rowClampB);

  const f16* pa0 = A + (long)ra0 * lda + seg * 8;
  const f16* pa1 = A + (long)ra1 * lda + seg * 8;
  const f16* pb0 = B + (long)rb0 * ldb + seg * 8;
  const f16* pb1 = B + (long)rb1 * ldb + seg * 8;

  f16x8 a0, a1, b0, b1;
  a0 = *(const f16x8*)(pa0);
  a1 = *(const f16x8*)(pa1);
  b0 = *(const f16x8*)(pb0);
  b1 = *(const f16x8*)(pb1);

  #pragma unroll 1
  for (int kt = 0; kt < kIters; ++kt) {
    __syncthreads();
    *(f16x8*)(As + r0 * 40 + seg * 8) = a0;
    *(f16x8*)(As + (r0 + 64) * 40 + seg * 8) = a1;
    *(f16x8*)(Bs + r0 * 40 + seg * 8) = b0;
    *(f16x8*)(Bs + (r0 + 64) * 40 + seg * 8) = b1;
    __syncthreads();
    if (kt + 1 < kIters) {
      const int kb = (kt + 1) * 32;
      a0 = *(const f16x8*)(pa0 + kb);
      a1 = *(const f16x8*)(pa1 + kb);
      b0 = *(const f16x8*)(pb0 + kb);
      b1 = *(const f16x8*)(pb1 + kb);
    }
    f16x8 af[4], bf[4];
    #pragma unroll
    for (int m = 0; m < 4; ++m)
      af[m] = *(const f16x8*)(As + (wr * 64 + m * 16 + fr) * 40 + fg * 8);
    #pragma unroll
    for (int n = 0; n < 4; ++n)
      bf[n] = *(const f16x8*)(Bs + (wc * 64 + n * 16 + fr) * 40 + fg * 8);
    #pragma unroll
    for (int m = 0; m < 4; ++m)
      #pragma unroll
      for (int n = 0; n < 4; ++n)
        acc[m][n] = __builtin_amdgcn_mfma_f32_16x16x32_f16(af[m], bf[n], acc[m][n], 0, 0, 0);
  }
}

// ---------------------------------------------------------------------------
// QKV GEMM, transposed (round-8 verbatim)
// ---------------------------------------------------------------------------
__global__ __launch_bounds__(256) void qkv_gemm(
    const f16* __restrict__ x_h, const f16* __restrict__ wq,
    const float* __restrict__ bn_a, const float* __restrict__ bn_sh,
    f16* __restrict__ qb, f16* __restrict__ kb, f16* __restrict__ vt)
{
  __shared__ f16 As[128 * 40];
  __shared__ f16 Bs[128 * 40];
  const int id = blockIdx.x + blockIdx.y * 8;          // [0,1048)
  const int lin = (id & 7) * 131 + (id >> 3);          // bijective [0,1048)
  const int row0 = (lin & 7) * 128;                    // channel block
  const int col0 = (lin >> 3) * 128;                   // token block (banded)
  f32x4 acc[4][4];
  #pragma unroll
  for (int m = 0; m < 4; ++m)
    #pragma unroll
    for (int n = 0; n < 4; ++n) acc[m][n] = (f32x4){0.f, 0.f, 0.f, 0.f};
  gemm_core(wq + (long)row0 * 512, x_h + (long)col0 * 512, 512, 512, 16,
            1 << 30, 16703 - col0, As, Bs, acc);
  const int lane = threadIdx.x & 63, wave = threadIdx.x >> 6;
  const int wr = wave >> 1, wc = wave & 1, fr = lane & 15, fg = lane >> 4;
  #pragma unroll
  for (int m = 0; m < 4; ++m) {
    const int chBase = row0 + wr * 64 + m * 16 + fg * 4;   // channel quad
    const float4 ba4 = *(const float4*)(bn_a + chBase);
    const float4 bs4 = *(const float4*)(bn_sh + chBase);
    const int hh = chBase >> 7, r = chBase & 127;          // quad-uniform cat
    #pragma unroll
    for (int n = 0; n < 4; ++n) {
      int tok = col0 + wc * 64 + n * 16 + fr;
      if (tok < 16704) {
        int bi = tok / 1044;
        int ni = tok - bi * 1044;
        long bh = (long)(bi * 8 + hh);
        float v0 = acc[m][n][0] * ba4.x + bs4.x;
        float v1 = acc[m][n][1] * ba4.y + bs4.y;
        float v2 = acc[m][n][2] * ba4.z + bs4.z;
        float v3 = acc[m][n][3] * ba4.w + bs4.w;
        if (r < 32) {
          f16x4 pk = {(f16)(v0 * QSCALE), (f16)(v1 * QSCALE),
                      (f16)(v2 * QSCALE), (f16)(v3 * QSCALE)};
          *(f16x4*)(qb + (bh * 1152 + ni) * 32 + r) = pk;
        } else if (r < 64) {
          f16x4 pk = {(f16)v0, (f16)v1, (f16)v2, (f16)v3};
          *(f16x4*)(kb + (bh * 1088 + ni) * 32 + (r - 32)) = pk;
        } else {
          f16* vp = vt + (bh * 64 + (r - 64)) * 1088 + ni;
          vp[0]        = (f16)v0;
          vp[1088]     = (f16)v1;
          vp[2 * 1088] = (f16)v2;
          vp[3 * 1088] = (f16)v3;
        }
      }
    }
  }
}

// ---------------------------------------------------------------------------
// depthwise conv branch (verbatim)
// ---------------------------------------------------------------------------
__global__ __launch_bounds__(256) void conv_kernel(
    const f16* __restrict__ vt, const float* __restrict__ conv_w,
    const float* __restrict__ conv_b, f16* __restrict__ vcT)
{
  __shared__ f16 img[16][34][36];
  const int b = blockIdx.y, g = blockIdx.x;
  const int c0 = g * 16, h = c0 >> 6, ci0 = c0 & 63;
  const int t = threadIdx.x;
  for (int i = t; i < 16 * 34 * 36; i += 256) ((f16*)img)[i] = (f16)0.f;
  __syncthreads();
  const int d = t >> 2, seg = t & 3;
  const f16* src = vt + ((long)(b * 8 + h) * 64 + d) * 1088 + ci0 * 16 + seg * 64;
  const int dhib = d >> 5;
  const int s2 = d & 31;
  #pragma unroll
  for (int j = 0; j < 8; ++j) {
    f16x8 vv = *(const f16x8*)(src + j * 8);
    #pragma unroll
    for (int e = 0; e < 8; ++e) {
      int local = seg * 64 + j * 8 + e;
      int cl = local >> 4, rr = local & 15;
      float xv = (float)vv[e];
      float hs = xv * fminf(fmaxf(xv + 3.f, 0.f), 6.f) * (1.f / 6.f);
      img[cl][1 + rr * 2 + dhib][1 + s2] = (f16)hs;
    }
  }
  __syncthreads();
  const int cl = t & 15, pg = t >> 4;
  const int c = c0 + cl;
  float w[9];
  #pragma unroll
  for (int i = 0; i < 9; ++i) w[i] = conv_w[c * 9 + i];
  const float bias = conv_b[c];
  for (int i = 0; i < 64; ++i) {
    int p = pg + i * 16;
    int s1 = p >> 5, ss2 = p & 31;
    float a = bias;
    #pragma unroll
    for (int di = 0; di < 3; ++di)
      #pragma unroll
      for (int dj = 0; dj < 3; ++dj)
        a += w[di * 3 + dj] * (float)img[cl][s1 + di][ss2 + dj];
    vcT[((long)b * 1024 + p) * 512 + c] = (f16)a;
  }
}

// ---------------------------------------------------------------------------
// fused attention v5: 64 q per wave (two q-groups), 2-wave 128-thread blocks.
// kf/vf LDS reads shared across both q-groups; two independent softmax chains
// per wave (2x ILP).  k-tile=32, 33 tiles, double-buffered LDS, setprio on PV.
// grid (9,128), XCD-grouped.
// ---------------------------------------------------------------------------
__global__ __launch_bounds__(128) void attn_kernel(
    const f16* __restrict__ qb, const f16* __restrict__ kb,
    const f16* __restrict__ vt, f16* __restrict__ opad)
{
  __shared__ f16 kls[2][4 * 32 * 8];   // 2 KB/buf
  __shared__ f16 vls[2][4 * 64 * 8];   // 4 KB/buf
  __shared__ float l_sh[2][64];

  const int id = blockIdx.x + blockIdx.y * 9;
  const int xcd = id & 7, sl = id >> 3;
  const int bh = xcd * 16 + sl / 9, qblk = sl % 9;
  const int b = bh >> 3, h = bh & 7;
  const int t = threadIdx.x;
  const int wave = t >> 6, lane = t & 63;
  const int lq = lane & 31, hi = lane >> 5;
  const int q0 = qblk * 128 + wave * 64;   // group A; group B = q0 + 32

  const f16* qb_ = qb + (long)bh * 1152 * 32;
  const f16* kb_ = kb + (long)bh * 1088 * 32;
  const f16* vt_ = vt + (long)bh * 64 * 1088;

  const f16x8 qfA0 = *(const f16x8*)(qb_ + (long)(q0 + lq) * 32 + hi * 8);
  const f16x8 qfA1 = *(const f16x8*)(qb_ + (long)(q0 + lq) * 32 + 16 + hi * 8);
  const f16x8 qfB0 = *(const f16x8*)(qb_ + (long)(q0 + 32 + lq) * 32 + hi * 8);
  const f16x8 qfB1 = *(const f16x8*)(qb_ + (long)(q0 + 32 + lq) * 32 + 16 + hi * 8);

  // staging (128 threads): K 16B/thread, V 32B/thread
  const int sk_k = t >> 2, sk_s = t & 3;
  const int sv_d = t >> 1, sv_p = t & 1;
  const int c0v = 2 * sv_p, c1v = c0v + 1;
  const int wkoff = (sk_s * 32 + ((sk_k + sk_s) & 31)) * 16;
  const int wvoff0 = (c0v * 64 + ((sv_d + c0v) & 63)) * 16;
  const int wvoff1 = (c1v * 64 + ((sv_d + c1v) & 63)) * 16;
  int koff[2], voff[2][2];
  #pragma unroll
  for (int ss = 0; ss < 2; ++ss) {
    int ss2 = 2 * ss + hi;
    koff[ss] = (ss2 * 32 + ((lq + ss2) & 31)) * 16;
  }
  #pragma unroll
  for (int nd = 0; nd < 2; ++nd)
    #pragma unroll
    for (int ks = 0; ks < 2; ++ks) {
      int kk4 = 2 * ks + hi;
      voff[nd][ks] = (kk4 * 64 + ((nd * 32 + lq + kk4) & 63)) * 16;
    }

  f16x8 stk, stv0, stv1;
  auto load_tile = [&](int kt) {
    stk  = *(const f16x8*)(kb_ + (long)(kt * 32 + sk_k) * 32 + sk_s * 8);
    stv0 = *(const f16x8*)(vt_ + (long)sv_d * 1088 + kt * 32 + sv_p * 16);
    stv1 = *(const f16x8*)(vt_ + (long)sv_d * 1088 + kt * 32 + sv_p * 16 + 8);
  };
  auto write_tile = [&](int buf) {
    *(f16x8*)((char*)kls[buf] + wkoff)  = stk;
    *(f16x8*)((char*)vls[buf] + wvoff0) = stv0;
    *(f16x8*)((char*)vls[buf] + wvoff1) = stv1;
  };

  f32x16 oA0 = zero16(), oA1 = zero16(), oB0 = zero16(), oB1 = zero16();
  float lsumA = 0.f, lsumB = 0.f;

  load_tile(0);
  write_tile(0);
  __syncthreads();

  int cur = 0;
  #pragma unroll 1
  for (int kt = 0; kt < 33; ++kt) {
    if (kt < 32) load_tile(kt + 1);
    const char* kcur = (const char*)kls[cur];
    const char* vcur = (const char*)vls[cur];
    f16x8 kf0 = *(const f16x8*)(kcur + koff[0]);
    f16x8 kf1 = *(const f16x8*)(kcur + koff[1]);
    // two independent S chains
    f32x16 sA = zero16(), sB = zero16();
    sA = __builtin_amdgcn_mfma_f32_32x32x16_f16(kf0, qfA0, sA, 0, 0, 0);
    sB = __builtin_amdgcn_mfma_f32_32x32x16_f16(kf0, qfB0, sB, 0, 0, 0);
    sA = __builtin_amdgcn_mfma_f32_32x32x16_f16(kf1, qfA1, sA, 0, 0, 0);
    sB = __builtin_amdgcn_mfma_f32_32x32x16_f16(kf1, qfB1, sB, 0, 0, 0);
    float pA[16], pB[16];
    #pragma unroll
    for (int r = 0; r < 16; ++r) { pA[r] = EXP2(sA[r]); pB[r] = EXP2(sB[r]); }
    if (kt == 32) {
      // last tile: valid k = 1024..1043 -> crow < 20
      #pragma unroll
      for (int r = 0; r < 16; ++r) {
        int cr = (r & 3) + 8 * (r >> 2) + 4 * hi;
        pA[r] = (cr < 20) ? pA[r] : 0.f;
        pB[r] = (cr < 20) ? pB[r] : 0.f;
      }
    }
    float t8[8];
    #pragma unroll
    for (int r = 0; r < 8; ++r) t8[r] = pA[r] + pA[r + 8];
    lsumA += ((t8[0] + t8[1]) + (t8[2] + t8[3])) + ((t8[4] + t8[5]) + (t8[6] + t8[7]));
    #pragma unroll
    for (int r = 0; r < 8; ++r) t8[r] = pB[r] + pB[r + 8];
    lsumB += ((t8[0] + t8[1]) + (t8[2] + t8[3])) + ((t8[4] + t8[5]) + (t8[6] + t8[7]));
    f16x8 paA0, paA1, paB0, paB1;
    pack_block(pA, paA0, paA1);
    pack_block(pB, paB0, paB1);
    __builtin_amdgcn_s_setprio(1);
    {
      f16x8 vf00 = *(const f16x8*)(vcur + voff[0][0]);
      f16x8 vf10 = *(const f16x8*)(vcur + voff[1][0]);
      oA0 = __builtin_amdgcn_mfma_f32_32x32x16_f16(paA0, vf00, oA0, 0, 0, 0);
      oB0 = __builtin_amdgcn_mfma_f32_32x32x16_f16(paB0, vf00, oB0, 0, 0, 0);
      oA1 = __builtin_amdgcn_mfma_f32_32x32x16_f16(paA0, vf10, oA1, 0, 0, 0);
      oB1 = __builtin_amdgcn_mfma_f32_32x32x16_f16(paB0, vf10, oB1, 0, 0, 0);
      f16x8 vf01 = *(const f16x8*)(vcur + voff[0][1]);
      f16x8 vf11 = *(const f16x8*)(vcur + voff[1][1]);
      oA0 = __builtin_amdgcn_mfma_f32_32x32x16_f16(paA1, vf01, oA0, 0, 0, 0);
      oB0 = __builtin_amdgcn_mfma_f32_32x32x16_f16(paB1, vf01, oB0, 0, 0, 0);
      oA1 = __builtin_amdgcn_mfma_f32_32x32x16_f16(paA1, vf11, oA1, 0, 0, 0);
      oB1 = __builtin_amdgcn_mfma_f32_32x32x16_f16(paB1, vf11, oB1, 0, 0, 0);
    }
    __builtin_amdgcn_s_setprio(0);
    if (kt < 32) write_tile(cur ^ 1);
    __syncthreads();
    cur ^= 1;
  }

  lsumA += __shfl_xor(lsumA, 32);
  lsumB += __shfl_xor(lsumB, 32);
  l_sh[wave][lq] = lsumA;
  l_sh[wave][32 + lq] = lsumB;
  __syncthreads();
  // scatter both groups: flat = q*512 + h*64 + d
  #pragma unroll
  for (int g = 0; g < 2; ++g) {
    #pragma unroll
    for (int nd = 0; nd < 2; ++nd) {
      #pragma unroll
      for (int r = 0; r < 16; ++r) {
        int cr = (r & 3) + 8 * (r >> 2) + 4 * hi;
        int q = q0 + g * 32 + cr;
        if (q < 1044) {
          float inv = __builtin_amdgcn_rcpf(l_sh[wave][g * 32 + cr]);
          float o = g ? (nd ? oB1[r] : oB0[r]) : (nd ? oA1[r] : oA0[r]);
          float val = o * inv;
          unsigned flat = (unsigned)q * 512u + (unsigned)h * 64u + (unsigned)(nd * 32 + lq);
          unsigned c = flat / 1044u;
          unsigned np = flat - c * 1044u;
          opad[((long)b * 512 + c) * 1056 + np] = (f16)val;
        }
      }
    }
  }
}

// ---------------------------------------------------------------------------
// proj GEMM (round-8 verbatim)
// ---------------------------------------------------------------------------
__global__ __launch_bounds__(256) void proj_gemm(
    const f16* __restrict__ pw, const f16* __restrict__ opad,
    const float* __restrict__ proj_b, const f16* __restrict__ vcT,
    f16* __restrict__ xoT)
{
  __shared__ f16 As[128 * 40];
  __shared__ f16 Bs[128 * 40];
  const int id = blockIdx.x + blockIdx.y * 4 + blockIdx.z * 32;  // [0,512)
  const int lin = (id & 7) * 64 + (id >> 3);                     // bijective
  const int b = lin >> 5;
  const int rc = lin & 31;
  const int row0 = (rc >> 2) * 128;  // m (image pixel)
  const int col0 = (rc & 3) * 128;   // c (channel)
  f32x4 acc[4][4];
  #pragma unroll
  for (int m = 0; m < 4; ++m)
    #pragma unroll
    for (int n = 0; n < 4; ++n) acc[m][n] = (f32x4){0.f, 0.f, 0.f, 0.f};
  gemm_core(pw + (long)row0 * 1056, opad + ((long)b * 512 + col0) * 1056,
            1056, 1056, 33, 1 << 30, 1 << 30, As, Bs, acc);
  const int lane = threadIdx.x & 63, wave = threadIdx.x >> 6;
  const int wr = wave >> 1, wc = wave & 1, fr = lane & 15, fg = lane >> 4;
  #pragma unroll
  for (int m = 0; m < 4; ++m) {
    #pragma unroll
    for (int rr = 0; rr < 4; ++rr) {
      int mi = row0 + wr * 64 + m * 16 + fg * 4 + rr;
      float pb = proj_b[mi];
      #pragma unroll
      for (int n = 0; n < 4; ++n) {
        int c = col0 + wc * 64 + n * 16 + fr;
        long idx = ((long)b * 1024 + mi) * 512 + c;
        xoT[idx] = (f16)(acc[m][n][rr] + pb + (float)vcT[idx]);
      }
    }
  }
}

// ---------------------------------------------------------------------------
// out GEMM (round-8 verbatim)
// ---------------------------------------------------------------------------
__global__ __launch_bounds__(256) void out_gemm(
    const f16* __restrict__ xoT, const f16* __restrict__ ow,
    const float* __restrict__ out_b, float* __restrict__ out)
{
  __shared__ f16 As[128 * 40];
  __shared__ f16 Bs[128 * 40];
  const int id = blockIdx.x + blockIdx.y * 4 + blockIdx.z * 32;  // [0,512)
  const int lin = (id & 7) * 64 + (id >> 3);                     // bijective
  const int b = lin >> 5;
  const int rc = lin & 31;
  const int row0 = (rc >> 2) * 128;
  const int col0 = (rc & 3) * 128;
  f32x4 acc[4][4];
  #pragma unroll
  for (int m = 0; m < 4; ++m)
    #pragma unroll
    for (int n = 0; n < 4; ++n) acc[m][n] = (f32x4){0.f, 0.f, 0.f, 0.f};
  gemm_core(xoT + ((long)b * 1024 + row0) * 512, ow + (long)col0 * 512,
            512, 512, 16, 1 << 30, 1 << 30, As, Bs, acc);
  const int lane = threadIdx.x & 63, wave = threadIdx.x >> 6;
  const int wr = wave >> 1, wc = wave & 1, fr = lane & 15, fg = lane >> 4;
  float ob[4];
  #pragma unroll
  for (int n = 0; n < 4; ++n) ob[n] = out_b[col0 + wc * 64 + n * 16 + fr];
  #pragma unroll
  for (int m = 0; m < 4; ++m) {
    #pragma unroll
    for (int rr = 0; rr < 4; ++rr) {
      int mi = row0 + wr * 64 + m * 16 + fg * 4 + rr;
      #pragma unroll
      for (int n = 0; n < 4; ++n) {
        int co = col0 + wc * 64 + n * 16 + fr;
        out[((long)b * 1024 + mi) * 512 + co] = acc[m][n][rr] + ob[n];
      }
    }
  }
}

// ---------------------------------------------------------------------------
extern "C" void kernel_launch(void* const* d_in, const int* in_sizes, int n_in,
                              void* d_out, int out_size, void* d_ws, size_t ws_size,
                              hipStream_t stream) {
  const float* x      = (const float*)d_in[0];
  const float* qkv_w  = (const float*)d_in[1];
  const float* bn_g   = (const float*)d_in[2];
  const float* bn_b   = (const float*)d_in[3];
  const float* bn_m   = (const float*)d_in[4];
  const float* bn_v   = (const float*)d_in[5];
  const float* conv_w = (const float*)d_in[6];
  const float* conv_b = (const float*)d_in[7];
  const float* proj_w = (const float*)d_in[8];
  const float* proj_b = (const float*)d_in[9];
  const float* out_w  = (const float*)d_in[10];
  const float* out_b  = (const float*)d_in[11];
  float* out = (float*)d_out;

  char* ws = (char*)d_ws;
  f16*   x_h   = (f16*)(ws + OFF_XH);
  f16*   wq_h  = (f16*)(ws + OFF_WQ);
  f16*   pw_h  = (f16*)(ws + OFF_PW);
  f16*   ow_h  = (f16*)(ws + OFF_OW);
  float* bn_a  = (float*)(ws + OFF_BNA);
  float* bn_sh = (float*)(ws + OFF_BNB);
  f16*   qb    = (f16*)(ws + OFF_QB);
  f16*   kb    = (f16*)(ws + OFF_KB);
  f16*   vt    = (f16*)(ws + OFF_VT);
  f16*   opad  = (f16*)(ws + OFF_OPAD);
  f16*   vcT   = (f16*)(ws + OFF_VCT);
  f16*   xoT   = (f16*)(ws + OFF_XOT);

  prep_kernel<<<1024, 256, 0, stream>>>(x, qkv_w, bn_g, bn_b, bn_m, bn_v,
                                        proj_w, out_w, x_h, wq_h, pw_h, ow_h,
                                        bn_a, bn_sh, qb, kb, vt, opad);
  qkv_gemm<<<dim3(8, 131), 256, 0, stream>>>(x_h, wq_h, bn_a, bn_sh, qb, kb, vt);
  conv_kernel<<<dim3(32, 16), 256, 0, stream>>>(vt, conv_w, conv_b, vcT);
  attn_kernel<<<dim3(9, 128), 128, 0, stream>>>(qb, kb, vt, opad);
  proj_gemm<<<dim3(4, 8, 16), 256, 0, stream>>>(pw_h, opad, proj_b, vcT, xoT);
  out_gemm<<<dim3(4, 8, 16), 256, 0, stream>>>(xoT, ow_h, out_b, out);
}

// Round 11
// 185.459 us; speedup vs baseline: 1.0714x; 1.0714x over previous
//
#include <hip/hip_runtime.h>
#include <hip/hip_fp16.h>

typedef _Float16 f16;
typedef _Float16 f16x8 __attribute__((ext_vector_type(8)));
typedef _Float16 f16x4 __attribute__((ext_vector_type(4)));
typedef float    f32x4 __attribute__((ext_vector_type(4)));
typedef float    f32x16 __attribute__((ext_vector_type(16)));

#define DEV __device__ __forceinline__

DEV int imin(int a, int b) { return a < b ? a : b; }

#if defined(__has_builtin)
#  if __has_builtin(__builtin_amdgcn_exp2f)
#    define EXP2(x) __builtin_amdgcn_exp2f(x)
#  else
#    define EXP2(x) __expf((x) * 0.6931471805599453f)
#  endif
#else
#  define EXP2(x) __expf((x) * 0.6931471805599453f)
#endif

// q pre-scale: (1/sqrt(32)) * log2(e) so softmax is p = 2^s
#define QSCALE (0.17677669529663687f * 1.4426950408889634f)

// ---------------------------------------------------------------------------
// Problem constants: B=16, N=1044, DIM=512, H=8, KD=32, D=64
// q padded to 1152 rows, k/v to 1088, o cols to 1056
// ---------------------------------------------------------------------------

// workspace offsets (bytes) — round-3/6 proven layout
constexpr size_t OFF_XH   = 0;            // x fp16 (16704,512)          17,104,896
constexpr size_t OFF_WQ   = 17104896;     // qkv_w fp16 (1024,512)        1,048,576
constexpr size_t OFF_PW   = 18153472;     // proj_w fp16 (1024,1056)      2,162,688
constexpr size_t OFF_OW   = 20316160;     // out_w fp16 (512,512)           524,288
constexpr size_t OFF_BNA  = 20840448;     // bn scale fp32 (1024)
constexpr size_t OFF_BNB  = 20844544;     // bn shift fp32 (1024)
constexpr size_t OFF_QB   = 20848640;     // q fp16 (128,1152,32)         9,437,184
constexpr size_t OFF_KB   = 30285824;     // k fp16 (128,1088,32)         8,912,896
constexpr size_t OFF_VT   = 39198720;     // v^T fp16 (128,64,1088)      17,825,792
constexpr size_t OFF_OPAD = 57024512;     // o fp16 (16,512,1056)        17,301,504
constexpr size_t OFF_VCT  = 74326016;     // vcT fp16 (16,1024,512)      16,777,216
constexpr size_t OFF_XOT  = 91103232;     // xoT fp16 (16,1024,512)      16,777,216

DEV f32x16 zero16() {
  f32x16 z;
  #pragma unroll
  for (int i = 0; i < 16; ++i) z[i] = 0.f;
  return z;
}

DEV unsigned pk2(float a, float b) {
  auto h = __builtin_amdgcn_cvt_pkrtz(a, b);
  union { decltype(h) x; unsigned u; } t;
  t.x = h;
  return t.u;
}

DEV void plswap(unsigned &a, unsigned &b) {
  asm("v_permlane32_swap_b32 %0, %1" : "+v"(a), "+v"(b));
}

union W4 { unsigned w[4]; f16x8 v; };

DEV void pack_block(const float p[16], f16x8 &a0, f16x8 &a1) {
  unsigned w0 = pk2(p[0], p[1]),   w1 = pk2(p[2], p[3]);
  unsigned w2 = pk2(p[4], p[5]),   w3 = pk2(p[6], p[7]);
  unsigned w4 = pk2(p[8], p[9]),   w5 = pk2(p[10], p[11]);
  unsigned w6 = pk2(p[12], p[13]), w7 = pk2(p[14], p[15]);
  plswap(w0, w2); plswap(w1, w3);
  plswap(w4, w6); plswap(w5, w7);
  W4 u; u.w[0] = w0; u.w[1] = w1; u.w[2] = w2; u.w[3] = w3; a0 = u.v;
  W4 v; v.w[0] = w4; v.w[1] = w5; v.w[2] = w6; v.w[3] = w7; a1 = v.v;
}

// ---------------------------------------------------------------------------
// prep (round-6/8 verbatim)
// ---------------------------------------------------------------------------
__global__ __launch_bounds__(256) void prep_kernel(
    const float* __restrict__ x, const float* __restrict__ qkv_w,
    const float* __restrict__ bn_g, const float* __restrict__ bn_b,
    const float* __restrict__ bn_m, const float* __restrict__ bn_v,
    const float* __restrict__ proj_w, const float* __restrict__ out_w,
    f16* __restrict__ x_h, f16* __restrict__ wq_h, f16* __restrict__ pw_h,
    f16* __restrict__ ow_h, float* __restrict__ bn_a, float* __restrict__ bn_sh,
    f16* __restrict__ qb, f16* __restrict__ kb, f16* __restrict__ vt,
    f16* __restrict__ opad)
{
  long tid = (long)blockIdx.x * blockDim.x + threadIdx.x;
  long gsz = (long)gridDim.x * blockDim.x;

  for (long i = tid; i < 2138112; i += gsz) {
    float4 f = ((const float4*)x)[i];
    f16x4 o = {(f16)f.x, (f16)f.y, (f16)f.z, (f16)f.w};
    ((f16x4*)x_h)[i] = o;
  }
  for (long i = tid; i < 524288; i += gsz) wq_h[i] = (f16)qkv_w[i];
  for (long i = tid; i < 1081344; i += gsz) {
    long m = i / 1056, nn = i - m * 1056;
    pw_h[i] = (nn < 1044) ? (f16)proj_w[m * 1044 + nn] : (f16)0.f;
  }
  for (long i = tid; i < 262144; i += gsz) ow_h[i] = (f16)out_w[i];
  for (long i = tid; i < 1024; i += gsz) {
    float a = bn_g[i] * rsqrtf(bn_v[i] + 1e-5f);
    bn_a[i] = a;
    bn_sh[i] = bn_b[i] - bn_m[i] * a;
  }
  for (long i = tid; i < 13824; i += gsz) {
    int bh = (int)(i / 108);
    int nn = 1044 + (int)(i - (long)bh * 108);
    f16* q = qb + ((long)bh * 1152 + nn) * 32;
    for (int j = 0; j < 32; ++j) q[j] = (f16)0.f;
  }
  for (long i = tid; i < 5632; i += gsz) {
    int bh = (int)(i / 44);
    int nn = 1044 + (int)(i - (long)bh * 44);
    f16* k = kb + ((long)bh * 1088 + nn) * 32;
    for (int j = 0; j < 32; ++j) k[j] = (f16)0.f;
  }
  for (long i = tid; i < 8192; i += gsz) {
    f16* v = vt + i * 1088 + 1044;
    for (int j = 0; j < 44; ++j) v[j] = (f16)0.f;
  }
  for (long i = tid; i < 8192; i += gsz) {
    f16* o = opad + i * 1056 + 1044;
    for (int j = 0; j < 12; ++j) o[j] = (f16)0.f;
  }
}

// ---------------------------------------------------------------------------
// shared 128x128xK NT-GEMM core (round-7/8 proven)
// ---------------------------------------------------------------------------
DEV void gemm_core(const f16* __restrict__ A, const f16* __restrict__ B,
                   int lda, int ldb, int kIters, int rowClampA, int rowClampB,
                   f16* As, f16* Bs, f32x4 acc[4][4])
{
  const int t = threadIdx.x;
  const int wave = t >> 6, lane = t & 63;
  const int wr = wave >> 1, wc = wave & 1;
  const int r0 = t >> 2, seg = t & 3;
  const int fr = lane & 15, fg = lane >> 4;
  const int ra0 = imin(r0, rowClampA);
  const int ra1 = imin(r0 + 64, rowClampA);
  const int rb0 = imin(r0, rowClampB);
  const int rb1 = imin(r0 + 64, rowClampB);

  const f16* pa0 = A + (long)ra0 * lda + seg * 8;
  const f16* pa1 = A + (long)ra1 * lda + seg * 8;
  const f16* pb0 = B + (long)rb0 * ldb + seg * 8;
  const f16* pb1 = B + (long)rb1 * ldb + seg * 8;

  f16x8 a0, a1, b0, b1;
  a0 = *(const f16x8*)(pa0);
  a1 = *(const f16x8*)(pa1);
  b0 = *(const f16x8*)(pb0);
  b1 = *(const f16x8*)(pb1);

  #pragma unroll 1
  for (int kt = 0; kt < kIters; ++kt) {
    __syncthreads();
    *(f16x8*)(As + r0 * 40 + seg * 8) = a0;
    *(f16x8*)(As + (r0 + 64) * 40 + seg * 8) = a1;
    *(f16x8*)(Bs + r0 * 40 + seg * 8) = b0;
    *(f16x8*)(Bs + (r0 + 64) * 40 + seg * 8) = b1;
    __syncthreads();
    if (kt + 1 < kIters) {
      const int kb = (kt + 1) * 32;
      a0 = *(const f16x8*)(pa0 + kb);
      a1 = *(const f16x8*)(pa1 + kb);
      b0 = *(const f16x8*)(pb0 + kb);
      b1 = *(const f16x8*)(pb1 + kb);
    }
    f16x8 af[4], bf[4];
    #pragma unroll
    for (int m = 0; m < 4; ++m)
      af[m] = *(const f16x8*)(As + (wr * 64 + m * 16 + fr) * 40 + fg * 8);
    #pragma unroll
    for (int n = 0; n < 4; ++n)
      bf[n] = *(const f16x8*)(Bs + (wc * 64 + n * 16 + fr) * 40 + fg * 8);
    #pragma unroll
    for (int m = 0; m < 4; ++m)
      #pragma unroll
      for (int n = 0; n < 4; ++n)
        acc[m][n] = __builtin_amdgcn_mfma_f32_16x16x32_f16(af[m], bf[n], acc[m][n], 0, 0, 0);
  }
}

// ---------------------------------------------------------------------------
// QKV GEMM, transposed (round-8 verbatim)
// ---------------------------------------------------------------------------
__global__ __launch_bounds__(256) void qkv_gemm(
    const f16* __restrict__ x_h, const f16* __restrict__ wq,
    const float* __restrict__ bn_a, const float* __restrict__ bn_sh,
    f16* __restrict__ qb, f16* __restrict__ kb, f16* __restrict__ vt)
{
  __shared__ f16 As[128 * 40];
  __shared__ f16 Bs[128 * 40];
  const int id = blockIdx.x + blockIdx.y * 8;          // [0,1048)
  const int lin = (id & 7) * 131 + (id >> 3);          // bijective [0,1048)
  const int row0 = (lin & 7) * 128;                    // channel block
  const int col0 = (lin >> 3) * 128;                   // token block (banded)
  f32x4 acc[4][4];
  #pragma unroll
  for (int m = 0; m < 4; ++m)
    #pragma unroll
    for (int n = 0; n < 4; ++n) acc[m][n] = (f32x4){0.f, 0.f, 0.f, 0.f};
  gemm_core(wq + (long)row0 * 512, x_h + (long)col0 * 512, 512, 512, 16,
            1 << 30, 16703 - col0, As, Bs, acc);
  const int lane = threadIdx.x & 63, wave = threadIdx.x >> 6;
  const int wr = wave >> 1, wc = wave & 1, fr = lane & 15, fg = lane >> 4;
  #pragma unroll
  for (int m = 0; m < 4; ++m) {
    const int chBase = row0 + wr * 64 + m * 16 + fg * 4;   // channel quad
    const float4 ba4 = *(const float4*)(bn_a + chBase);
    const float4 bs4 = *(const float4*)(bn_sh + chBase);
    const int hh = chBase >> 7, r = chBase & 127;          // quad-uniform cat
    #pragma unroll
    for (int n = 0; n < 4; ++n) {
      int tok = col0 + wc * 64 + n * 16 + fr;
      if (tok < 16704) {
        int bi = tok / 1044;
        int ni = tok - bi * 1044;
        long bh = (long)(bi * 8 + hh);
        float v0 = acc[m][n][0] * ba4.x + bs4.x;
        float v1 = acc[m][n][1] * ba4.y + bs4.y;
        float v2 = acc[m][n][2] * ba4.z + bs4.z;
        float v3 = acc[m][n][3] * ba4.w + bs4.w;
        if (r < 32) {
          f16x4 pk = {(f16)(v0 * QSCALE), (f16)(v1 * QSCALE),
                      (f16)(v2 * QSCALE), (f16)(v3 * QSCALE)};
          *(f16x4*)(qb + (bh * 1152 + ni) * 32 + r) = pk;
        } else if (r < 64) {
          f16x4 pk = {(f16)v0, (f16)v1, (f16)v2, (f16)v3};
          *(f16x4*)(kb + (bh * 1088 + ni) * 32 + (r - 32)) = pk;
        } else {
          f16* vp = vt + (bh * 64 + (r - 64)) * 1088 + ni;
          vp[0]        = (f16)v0;
          vp[1088]     = (f16)v1;
          vp[2 * 1088] = (f16)v2;
          vp[3 * 1088] = (f16)v3;
        }
      }
    }
  }
}

// ---------------------------------------------------------------------------
// depthwise conv branch (verbatim)
// ---------------------------------------------------------------------------
__global__ __launch_bounds__(256) void conv_kernel(
    const f16* __restrict__ vt, const float* __restrict__ conv_w,
    const float* __restrict__ conv_b, f16* __restrict__ vcT)
{
  __shared__ f16 img[16][34][36];
  const int b = blockIdx.y, g = blockIdx.x;
  const int c0 = g * 16, h = c0 >> 6, ci0 = c0 & 63;
  const int t = threadIdx.x;
  for (int i = t; i < 16 * 34 * 36; i += 256) ((f16*)img)[i] = (f16)0.f;
  __syncthreads();
  const int d = t >> 2, seg = t & 3;
  const f16* src = vt + ((long)(b * 8 + h) * 64 + d) * 1088 + ci0 * 16 + seg * 64;
  const int dhib = d >> 5;
  const int s2 = d & 31;
  #pragma unroll
  for (int j = 0; j < 8; ++j) {
    f16x8 vv = *(const f16x8*)(src + j * 8);
    #pragma unroll
    for (int e = 0; e < 8; ++e) {
      int local = seg * 64 + j * 8 + e;
      int cl = local >> 4, rr = local & 15;
      float xv = (float)vv[e];
      float hs = xv * fminf(fmaxf(xv + 3.f, 0.f), 6.f) * (1.f / 6.f);
      img[cl][1 + rr * 2 + dhib][1 + s2] = (f16)hs;
    }
  }
  __syncthreads();
  const int cl = t & 15, pg = t >> 4;
  const int c = c0 + cl;
  float w[9];
  #pragma unroll
  for (int i = 0; i < 9; ++i) w[i] = conv_w[c * 9 + i];
  const float bias = conv_b[c];
  for (int i = 0; i < 64; ++i) {
    int p = pg + i * 16;
    int s1 = p >> 5, ss2 = p & 31;
    float a = bias;
    #pragma unroll
    for (int di = 0; di < 3; ++di)
      #pragma unroll
      for (int dj = 0; dj < 3; ++dj)
        a += w[di * 3 + dj] * (float)img[cl][s1 + di][ss2 + dj];
    vcT[((long)b * 1024 + p) * 512 + c] = (f16)a;
  }
}

// ---------------------------------------------------------------------------
// fused attention v6: BARRIER-FREE wave-private staging.  4 waves/block,
// 32 q per wave (r9 work split), each wave double-buffers its OWN K/V tile
// in a private LDS slice — all LDS deps are intra-wave (compiler-ordered via
// lgkmcnt/vmcnt), zero __syncthreads.  Same proven swizzles/masks as r9.
// grid (9,128), XCD-grouped.
// ---------------------------------------------------------------------------
__global__ __launch_bounds__(256) void attn_kernel(
    const f16* __restrict__ qb, const f16* __restrict__ kb,
    const f16* __restrict__ vt, f16* __restrict__ opad)
{
  __shared__ f16 kls[4][2][4 * 32 * 8];   // [wave][buf] 2 KB each
  __shared__ f16 vls[4][2][4 * 64 * 8];   // [wave][buf] 4 KB each
  __shared__ float l_sh[4][32];

  const int id = blockIdx.x + blockIdx.y * 9;
  const int xcd = id & 7, sl = id >> 3;
  const int bh = xcd * 16 + sl / 9, qblk = sl % 9;
  const int b = bh >> 3, h = bh & 7;
  const int t = threadIdx.x;
  const int wave = t >> 6, lane = t & 63;
  const int lq = lane & 31, hi = lane >> 5;
  const int q0 = qblk * 128 + wave * 32;

  const f16* qb_ = qb + (long)bh * 1152 * 32;
  const f16* kb_ = kb + (long)bh * 1088 * 32;
  const f16* vt_ = vt + (long)bh * 64 * 1088;

  const f16x8 qf0 = *(const f16x8*)(qb_ + (long)(q0 + lq) * 32 + hi * 8);
  const f16x8 qf1 = *(const f16x8*)(qb_ + (long)(q0 + lq) * 32 + 16 + hi * 8);

  // wave-private staging maps.
  // K tile (32 rows x 32 kd f16): lane covers row rk = lane>>1, 2 chunks of
  // 16B starting at chunk ckb = (lane&1)*2.  slot = [chunk][ (row+chunk)&31 ]
  const int rk = lane >> 1;
  const int ckb = (lane & 1) * 2;
  const int kwo0 = (ckb * 32 + ((rk + ckb) & 31)) * 16;
  const int kwo1 = ((ckb + 1) * 32 + ((rk + ckb + 1) & 31)) * 16;
  // V tile (64 d-rows x 32 k f16): 4 passes p, d = p*16 + (lane>>2),
  // k-chunk cv = lane&3.  slot = [cv][ (d+cv)&63 ]
  const int dv = lane >> 2, cv = lane & 3;
  int vwo[4];
  #pragma unroll
  for (int p = 0; p < 4; ++p)
    vwo[p] = (cv * 64 + ((p * 16 + dv + cv) & 63)) * 16;
  // frag read offsets (r9-proven formulas)
  int koff[2], voff[2][2];
  #pragma unroll
  for (int ss = 0; ss < 2; ++ss) {
    int ss2 = 2 * ss + hi;
    koff[ss] = (ss2 * 32 + ((lq + ss2) & 31)) * 16;
  }
  #pragma unroll
  for (int nd = 0; nd < 2; ++nd)
    #pragma unroll
    for (int ks = 0; ks < 2; ++ks) {
      int kk4 = 2 * ks + hi;
      voff[nd][ks] = (kk4 * 64 + ((nd * 32 + lq + kk4) & 63)) * 16;
    }

  f16* kbuf0 = kls[wave][0]; f16* kbuf1 = kls[wave][1];
  f16* vbuf0 = vls[wave][0]; f16* vbuf1 = vls[wave][1];

  f16x8 stk0, stk1, stv0, stv1, stv2, stv3;
  auto load_tile = [&](int kt) {
    const f16* krow = kb_ + (long)(kt * 32 + rk) * 32 + ckb * 8;
    stk0 = *(const f16x8*)(krow);
    stk1 = *(const f16x8*)(krow + 8);
    const f16* vb = vt_ + (long)dv * 1088 + kt * 32 + cv * 8;
    stv0 = *(const f16x8*)(vb);
    stv1 = *(const f16x8*)(vb + 16 * 1088);
    stv2 = *(const f16x8*)(vb + 32 * 1088);
    stv3 = *(const f16x8*)(vb + 48 * 1088);
  };
  auto write_tile = [&](f16* kd, f16* vd) {
    *(f16x8*)((char*)kd + kwo0) = stk0;
    *(f16x8*)((char*)kd + kwo1) = stk1;
    *(f16x8*)((char*)vd + vwo[0]) = stv0;
    *(f16x8*)((char*)vd + vwo[1]) = stv1;
    *(f16x8*)((char*)vd + vwo[2]) = stv2;
    *(f16x8*)((char*)vd + vwo[3]) = stv3;
  };

  f32x16 o0 = zero16(), o1 = zero16();
  float lsum = 0.f;

  load_tile(0);
  write_tile(kbuf0, vbuf0);

  int cur = 0;
  #pragma unroll 1
  for (int kt = 0; kt < 33; ++kt) {
    if (kt < 32) load_tile(kt + 1);
    const char* kcur = (const char*)(cur ? kbuf1 : kbuf0);
    const char* vcur = (const char*)(cur ? vbuf1 : vbuf0);
    f16x8 kf0 = *(const f16x8*)(kcur + koff[0]);
    f16x8 kf1 = *(const f16x8*)(kcur + koff[1]);
    f32x16 s = zero16();
    s = __builtin_amdgcn_mfma_f32_32x32x16_f16(kf0, qf0, s, 0, 0, 0);
    s = __builtin_amdgcn_mfma_f32_32x32x16_f16(kf1, qf1, s, 0, 0, 0);
    float p[16];
    #pragma unroll
    for (int r = 0; r < 16; ++r) p[r] = EXP2(s[r]);
    if (kt == 32) {
      // last tile: valid k = 1024..1043 -> crow < 20
      #pragma unroll
      for (int r = 0; r < 16; ++r) {
        int cr = (r & 3) + 8 * (r >> 2) + 4 * hi;
        p[r] = (cr < 20) ? p[r] : 0.f;
      }
    }
    float t8[8];
    #pragma unroll
    for (int r = 0; r < 8; ++r) t8[r] = p[r] + p[r + 8];
    lsum += ((t8[0] + t8[1]) + (t8[2] + t8[3])) + ((t8[4] + t8[5]) + (t8[6] + t8[7]));
    f16x8 pa0, pa1;
    pack_block(p, pa0, pa1);
    __builtin_amdgcn_s_setprio(1);
    {
      f16x8 vf00 = *(const f16x8*)(vcur + voff[0][0]);
      f16x8 vf10 = *(const f16x8*)(vcur + voff[1][0]);
      o0 = __builtin_amdgcn_mfma_f32_32x32x16_f16(pa0, vf00, o0, 0, 0, 0);
      o1 = __builtin_amdgcn_mfma_f32_32x32x16_f16(pa0, vf10, o1, 0, 0, 0);
      f16x8 vf01 = *(const f16x8*)(vcur + voff[0][1]);
      f16x8 vf11 = *(const f16x8*)(vcur + voff[1][1]);
      o0 = __builtin_amdgcn_mfma_f32_32x32x16_f16(pa1, vf01, o0, 0, 0, 0);
      o1 = __builtin_amdgcn_mfma_f32_32x32x16_f16(pa1, vf11, o1, 0, 0, 0);
    }
    __builtin_amdgcn_s_setprio(0);
    if (kt < 32) write_tile(cur ? kbuf0 : kbuf1, cur ? vbuf0 : vbuf1);
    cur ^= 1;
  }

  // intra-wave cross-lane l gather (no barrier needed: same wave)
  lsum += __shfl_xor(lsum, 32);
  l_sh[wave][lq] = lsum;
  float invl[16];
  #pragma unroll
  for (int r = 0; r < 16; ++r) {
    int cr = (r & 3) + 8 * (r >> 2) + 4 * hi;
    invl[r] = __builtin_amdgcn_rcpf(l_sh[wave][cr]);
  }
  // scatter O through torch raw reshape: flat = q*512 + h*64 + d
  #pragma unroll
  for (int nd = 0; nd < 2; ++nd) {
    #pragma unroll
    for (int r = 0; r < 16; ++r) {
      int cr = (r & 3) + 8 * (r >> 2) + 4 * hi;
      int q = q0 + cr;
      if (q < 1044) {
        float val = (nd ? o1[r] : o0[r]) * invl[r];
        unsigned flat = (unsigned)q * 512u + (unsigned)h * 64u + (unsigned)(nd * 32 + lq);
        unsigned c = flat / 1044u;
        unsigned np = flat - c * 1044u;
        opad[((long)b * 512 + c) * 1056 + np] = (f16)val;
      }
    }
  }
}

// ---------------------------------------------------------------------------
// proj GEMM (round-8 verbatim)
// ---------------------------------------------------------------------------
__global__ __launch_bounds__(256) void proj_gemm(
    const f16* __restrict__ pw, const f16* __restrict__ opad,
    const float* __restrict__ proj_b, const f16* __restrict__ vcT,
    f16* __restrict__ xoT)
{
  __shared__ f16 As[128 * 40];
  __shared__ f16 Bs[128 * 40];
  const int id = blockIdx.x + blockIdx.y * 4 + blockIdx.z * 32;  // [0,512)
  const int lin = (id & 7) * 64 + (id >> 3);                     // bijective
  const int b = lin >> 5;
  const int rc = lin & 31;
  const int row0 = (rc >> 2) * 128;  // m (image pixel)
  const int col0 = (rc & 3) * 128;   // c (channel)
  f32x4 acc[4][4];
  #pragma unroll
  for (int m = 0; m < 4; ++m)
    #pragma unroll
    for (int n = 0; n < 4; ++n) acc[m][n] = (f32x4){0.f, 0.f, 0.f, 0.f};
  gemm_core(pw + (long)row0 * 1056, opad + ((long)b * 512 + col0) * 1056,
            1056, 1056, 33, 1 << 30, 1 << 30, As, Bs, acc);
  const int lane = threadIdx.x & 63, wave = threadIdx.x >> 6;
  const int wr = wave >> 1, wc = wave & 1, fr = lane & 15, fg = lane >> 4;
  #pragma unroll
  for (int m = 0; m < 4; ++m) {
    #pragma unroll
    for (int rr = 0; rr < 4; ++rr) {
      int mi = row0 + wr * 64 + m * 16 + fg * 4 + rr;
      float pb = proj_b[mi];
      #pragma unroll
      for (int n = 0; n < 4; ++n) {
        int c = col0 + wc * 64 + n * 16 + fr;
        long idx = ((long)b * 1024 + mi) * 512 + c;
        xoT[idx] = (f16)(acc[m][n][rr] + pb + (float)vcT[idx]);
      }
    }
  }
}

// ---------------------------------------------------------------------------
// out GEMM (round-8 verbatim)
// ---------------------------------------------------------------------------
__global__ __launch_bounds__(256) void out_gemm(
    const f16* __restrict__ xoT, const f16* __restrict__ ow,
    const float* __restrict__ out_b, float* __restrict__ out)
{
  __shared__ f16 As[128 * 40];
  __shared__ f16 Bs[128 * 40];
  const int id = blockIdx.x + blockIdx.y * 4 + blockIdx.z * 32;  // [0,512)
  const int lin = (id & 7) * 64 + (id >> 3);                     // bijective
  const int b = lin >> 5;
  const int rc = lin & 31;
  const int row0 = (rc >> 2) * 128;
  const int col0 = (rc & 3) * 128;
  f32x4 acc[4][4];
  #pragma unroll
  for (int m = 0; m < 4; ++m)
    #pragma unroll
    for (int n = 0; n < 4; ++n) acc[m][n] = (f32x4){0.f, 0.f, 0.f, 0.f};
  gemm_core(xoT + ((long)b * 1024 + row0) * 512, ow + (long)col0 * 512,
            512, 512, 16, 1 << 30, 1 << 30, As, Bs, acc);
  const int lane = threadIdx.x & 63, wave = threadIdx.x >> 6;
  const int wr = wave >> 1, wc = wave & 1, fr = lane & 15, fg = lane >> 4;
  float ob[4];
  #pragma unroll
  for (int n = 0; n < 4; ++n) ob[n] = out_b[col0 + wc * 64 + n * 16 + fr];
  #pragma unroll
  for (int m = 0; m < 4; ++m) {
    #pragma unroll
    for (int rr = 0; rr < 4; ++rr) {
      int mi = row0 + wr * 64 + m * 16 + fg * 4 + rr;
      #pragma unroll
      for (int n = 0; n < 4; ++n) {
        int co = col0 + wc * 64 + n * 16 + fr;
        out[((long)b * 1024 + mi) * 512 + co] = acc[m][n][rr] + ob[n];
      }
    }
  }
}

// ---------------------------------------------------------------------------
extern "C" void kernel_launch(void* const* d_in, const int* in_sizes, int n_in,
                              void* d_out, int out_size, void* d_ws, size_t ws_size,
                              hipStream_t stream) {
  const float* x      = (const float*)d_in[0];
  const float* qkv_w  = (const float*)d_in[1];
  const float* bn_g   = (const float*)d_in[2];
  const float* bn_b   = (const float*)d_in[3];
  const float* bn_m   = (const float*)d_in[4];
  const float* bn_v   = (const float*)d_in[5];
  const float* conv_w = (const float*)d_in[6];
  const float* conv_b = (const float*)d_in[7];
  const float* proj_w = (const float*)d_in[8];
  const float* proj_b = (const float*)d_in[9];
  const float* out_w  = (const float*)d_in[10];
  const float* out_b  = (const float*)d_in[11];
  float* out = (float*)d_out;

  char* ws = (char*)d_ws;
  f16*   x_h   = (f16*)(ws + OFF_XH);
  f16*   wq_h  = (f16*)(ws + OFF_WQ);
  f16*   pw_h  = (f16*)(ws + OFF_PW);
  f16*   ow_h  = (f16*)(ws + OFF_OW);
  float* bn_a  = (float*)(ws + OFF_BNA);
  float* bn_sh = (float*)(ws + OFF_BNB);
  f16*   qb    = (f16*)(ws + OFF_QB);
  f16*   kb    = (f16*)(ws + OFF_KB);
  f16*   vt    = (f16*)(ws + OFF_VT);
  f16*   opad  = (f16*)(ws + OFF_OPAD);
  f16*   vcT   = (f16*)(ws + OFF_VCT);
  f16*   xoT   = (f16*)(ws + OFF_XOT);

  prep_kernel<<<1024, 256, 0, stream>>>(x, qkv_w, bn_g, bn_b, bn_m, bn_v,
                                        proj_w, out_w, x_h, wq_h, pw_h, ow_h,
                                        bn_a, bn_sh, qb, kb, vt, opad);
  qkv_gemm<<<dim3(8, 131), 256, 0, stream>>>(x_h, wq_h, bn_a, bn_sh, qb, kb, vt);
  conv_kernel<<<dim3(32, 16), 256, 0, stream>>>(vt, conv_w, conv_b, vcT);
  attn_kernel<<<dim3(9, 128), 256, 0, stream>>>(qb, kb, vt, opad);
  proj_gemm<<<dim3(4, 8, 16), 256, 0, stream>>>(pw_h, opad, proj_b, vcT, xoT);
  out_gemm<<<dim3(4, 8, 16), 256, 0, stream>>>(xoT, ow_h, out_b, out);
}

// Round 12
// 184.106 us; speedup vs baseline: 1.0793x; 1.0073x over previous
//
#include <hip/hip_runtime.h>
#include <hip/hip_fp16.h>

typedef _Float16 f16;
typedef _Float16 f16x8 __attribute__((ext_vector_type(8)));
typedef _Float16 f16x4 __attribute__((ext_vector_type(4)));
typedef float    f32x4 __attribute__((ext_vector_type(4)));
typedef float    f32x16 __attribute__((ext_vector_type(16)));

#define DEV __device__ __forceinline__

DEV int imin(int a, int b) { return a < b ? a : b; }

#if defined(__has_builtin)
#  if __has_builtin(__builtin_amdgcn_exp2f)
#    define EXP2(x) __builtin_amdgcn_exp2f(x)
#  else
#    define EXP2(x) __expf((x) * 0.6931471805599453f)
#  endif
#else
#  define EXP2(x) __expf((x) * 0.6931471805599453f)
#endif

// q pre-scale: (1/sqrt(32)) * log2(e) so softmax is p = 2^s
#define QSCALE (0.17677669529663687f * 1.4426950408889634f)

// ---------------------------------------------------------------------------
// Problem constants: B=16, N=1044, DIM=512, H=8, KD=32, D=64
// q padded to 1152 rows, k/v to 1088, o cols to 1056
// ---------------------------------------------------------------------------

// workspace offsets (bytes) — same layout; WQF/PWF/OWF are frag-major weights
// (identical sizes to the old wq_h/pw_h/ow_h so offsets are unchanged)
constexpr size_t OFF_XH   = 0;            // x fp16 (16704,512)          17,104,896
constexpr size_t OFF_WQF  = 17104896;     // wq frags  8*16*8*1KB         1,048,576
constexpr size_t OFF_PWF  = 18153472;     // pw frags  8*33*8*1KB         2,162,688
constexpr size_t OFF_OWF  = 20316160;     // ow frags  4*16*8*1KB           524,288
constexpr size_t OFF_BNA  = 20840448;     // bn scale fp32 (1024)
constexpr size_t OFF_BNB  = 20844544;     // bn shift fp32 (1024)
constexpr size_t OFF_QB   = 20848640;     // q fp16 (128,1152,32)         9,437,184
constexpr size_t OFF_KB   = 30285824;     // k fp16 (128,1088,32)         8,912,896
constexpr size_t OFF_VT   = 39198720;     // v^T fp16 (128,64,1088)      17,825,792
constexpr size_t OFF_OPAD = 57024512;     // o fp16 (16,512,1056)        17,301,504
constexpr size_t OFF_VCT  = 74326016;     // vcT fp16 (16,1024,512)      16,777,216
constexpr size_t OFF_XOT  = 91103232;     // xoT fp16 (16,1024,512)      16,777,216

DEV f32x16 zero16() {
  f32x16 z;
  #pragma unroll
  for (int i = 0; i < 16; ++i) z[i] = 0.f;
  return z;
}

DEV unsigned pk2(float a, float b) {
  auto h = __builtin_amdgcn_cvt_pkrtz(a, b);
  union { decltype(h) x; unsigned u; } t;
  t.x = h;
  return t.u;
}

DEV void plswap(unsigned &a, unsigned &b) {
  asm("v_permlane32_swap_b32 %0, %1" : "+v"(a), "+v"(b));
}

union W4 { unsigned w[4]; f16x8 v; };

DEV void pack_block(const float p[16], f16x8 &a0, f16x8 &a1) {
  unsigned w0 = pk2(p[0], p[1]),   w1 = pk2(p[2], p[3]);
  unsigned w2 = pk2(p[4], p[5]),   w3 = pk2(p[6], p[7]);
  unsigned w4 = pk2(p[8], p[9]),   w5 = pk2(p[10], p[11]);
  unsigned w6 = pk2(p[12], p[13]), w7 = pk2(p[14], p[15]);
  plswap(w0, w2); plswap(w1, w3);
  plswap(w4, w6); plswap(w5, w7);
  W4 u; u.w[0] = w0; u.w[1] = w1; u.w[2] = w2; u.w[3] = w3; a0 = u.v;
  W4 v; v.w[0] = w4; v.w[1] = w5; v.w[2] = w6; v.w[3] = w7; a1 = v.v;
}

// ---------------------------------------------------------------------------
// prep: x fp16 convert, BN fold, zero pads, weight FRAGMENT layouts.
// Frag element map (derived from the proven LDS frag reads):
//   chunk(blk,kt,g,m,lane)[e] = W[blk*128 + g*64 + m*16 + (lane&15)]
//                                [kt*32 + (lane>>4)*8 + e]
// stored at flat ((.. per-blk: (kt*8+g*4+m)*64 + lane) * 8 f16.
// ---------------------------------------------------------------------------
__global__ __launch_bounds__(256) void prep_kernel(
    const float* __restrict__ x, const float* __restrict__ qkv_w,
    const float* __restrict__ bn_g, const float* __restrict__ bn_b,
    const float* __restrict__ bn_m, const float* __restrict__ bn_v,
    const float* __restrict__ proj_w, const float* __restrict__ out_w,
    f16* __restrict__ x_h, f16* __restrict__ wqF, f16* __restrict__ pwF,
    f16* __restrict__ owF, float* __restrict__ bn_a, float* __restrict__ bn_sh,
    f16* __restrict__ qb, f16* __restrict__ kb, f16* __restrict__ vt,
    f16* __restrict__ opad)
{
  long tid = (long)blockIdx.x * blockDim.x + threadIdx.x;
  long gsz = (long)gridDim.x * blockDim.x;

  for (long i = tid; i < 2138112; i += gsz) {
    float4 f = ((const float4*)x)[i];
    f16x4 o = {(f16)f.x, (f16)f.y, (f16)f.z, (f16)f.w};
    ((f16x4*)x_h)[i] = o;
  }
  // wqF: 8 blk x 16 kt x 8 frag x 64 lanes = 65536 chunks
  for (long i = tid; i < 65536; i += gsz) {
    int lane = (int)(i & 63);
    int f = (int)(i >> 6);
    int m = f & 3, g = (f >> 2) & 1, kt = (f >> 3) & 15, blk = f >> 7;
    int ch = blk * 128 + g * 64 + m * 16 + (lane & 15);
    int k  = kt * 32 + (lane >> 4) * 8;
    const float* src = qkv_w + (long)ch * 512 + k;
    f16x8 d;
    #pragma unroll
    for (int e = 0; e < 8; ++e) d[e] = (f16)src[e];
    *(f16x8*)(wqF + i * 8) = d;
  }
  // pwF: 8 blk x 33 kt x 8 frag x 64 lanes = 135168 chunks (K padded 1056)
  for (long i = tid; i < 135168; i += gsz) {
    int lane = (int)(i & 63);
    int f = (int)(i >> 6);
    int m = f & 3, g = (f >> 2) & 1;
    int rest = f >> 3;
    int kt = rest % 33, blk = rest / 33;
    int mrow = blk * 128 + g * 64 + m * 16 + (lane & 15);
    int k = kt * 32 + (lane >> 4) * 8;
    f16x8 d;
    #pragma unroll
    for (int e = 0; e < 8; ++e) {
      int kk = k + e;
      d[e] = (kk < 1044) ? (f16)proj_w[(long)mrow * 1044 + kk] : (f16)0.f;
    }
    *(f16x8*)(pwF + i * 8) = d;
  }
  // owF: 4 blk x 16 kt x 8 frag x 64 lanes = 32768 chunks
  for (long i = tid; i < 32768; i += gsz) {
    int lane = (int)(i & 63);
    int f = (int)(i >> 6);
    int n = f & 3, g = (f >> 2) & 1, kt = (f >> 3) & 15, blk = f >> 7;
    int co = blk * 128 + g * 64 + n * 16 + (lane & 15);
    int k = kt * 32 + (lane >> 4) * 8;
    const float* src = out_w + (long)co * 512 + k;
    f16x8 d;
    #pragma unroll
    for (int e = 0; e < 8; ++e) d[e] = (f16)src[e];
    *(f16x8*)(owF + i * 8) = d;
  }
  for (long i = tid; i < 1024; i += gsz) {
    float a = bn_g[i] * rsqrtf(bn_v[i] + 1e-5f);
    bn_a[i] = a;
    bn_sh[i] = bn_b[i] - bn_m[i] * a;
  }
  for (long i = tid; i < 13824; i += gsz) {
    int bh = (int)(i / 108);
    int nn = 1044 + (int)(i - (long)bh * 108);
    f16* q = qb + ((long)bh * 1152 + nn) * 32;
    for (int j = 0; j < 32; ++j) q[j] = (f16)0.f;
  }
  for (long i = tid; i < 5632; i += gsz) {
    int bh = (int)(i / 44);
    int nn = 1044 + (int)(i - (long)bh * 44);
    f16* k = kb + ((long)bh * 1088 + nn) * 32;
    for (int j = 0; j < 32; ++j) k[j] = (f16)0.f;
  }
  for (long i = tid; i < 8192; i += gsz) {
    f16* v = vt + i * 1088 + 1044;
    for (int j = 0; j < 44; ++j) v[j] = (f16)0.f;
  }
  for (long i = tid; i < 8192; i += gsz) {
    f16* o = opad + i * 1056 + 1044;
    for (int j = 0; j < 12; ++j) o[j] = (f16)0.f;
  }
}

// ---------------------------------------------------------------------------
// GEMM core, A-side FRAGGED (weights direct from L2, coalesced b128),
// B-side LDS-staged (proven r7 pipeline: single buffer, 2 barriers, T14).
// ---------------------------------------------------------------------------
DEV void gemm_coreA(const f16* __restrict__ AF, const f16* __restrict__ B,
                    long ldb, int kIters, int rowClampB,
                    f16* Bs, f32x4 acc[4][4])
{
  const int t = threadIdx.x;
  const int wave = t >> 6, lane = t & 63;
  const int wr = wave >> 1, wc = wave & 1;
  const int r0 = t >> 2, seg = t & 3;
  const int fr = lane & 15, fg = lane >> 4;
  const int rb0 = imin(r0, rowClampB);
  const int rb1 = imin(r0 + 64, rowClampB);
  const f16* pb0 = B + (long)rb0 * ldb + seg * 8;
  const f16* pb1 = B + (long)rb1 * ldb + seg * 8;
  const f16* afp = AF + (long)(wr * 4) * 512 + (long)lane * 8;

  f16x8 b0 = *(const f16x8*)(pb0);
  f16x8 b1 = *(const f16x8*)(pb1);

  #pragma unroll 1
  for (int kt = 0; kt < kIters; ++kt) {
    __syncthreads();
    *(f16x8*)(Bs + r0 * 40 + seg * 8) = b0;
    *(f16x8*)(Bs + (r0 + 64) * 40 + seg * 8) = b1;
    __syncthreads();
    f16x8 af[4];
    #pragma unroll
    for (int m = 0; m < 4; ++m)
      af[m] = *(const f16x8*)(afp + (long)(kt * 8 + m) * 512);
    if (kt + 1 < kIters) {
      const int kb = (kt + 1) * 32;
      b0 = *(const f16x8*)(pb0 + kb);
      b1 = *(const f16x8*)(pb1 + kb);
    }
    f16x8 bf[4];
    #pragma unroll
    for (int n = 0; n < 4; ++n)
      bf[n] = *(const f16x8*)(Bs + (wc * 64 + n * 16 + fr) * 40 + fg * 8);
    #pragma unroll
    for (int m = 0; m < 4; ++m)
      #pragma unroll
      for (int n = 0; n < 4; ++n)
        acc[m][n] = __builtin_amdgcn_mfma_f32_16x16x32_f16(af[m], bf[n], acc[m][n], 0, 0, 0);
  }
}

// ---------------------------------------------------------------------------
// GEMM core, B-side FRAGGED (weights), A-side LDS-staged.
// ---------------------------------------------------------------------------
DEV void gemm_coreB(const f16* __restrict__ A, const f16* __restrict__ BF,
                    long lda, int kIters,
                    f16* As, f32x4 acc[4][4])
{
  const int t = threadIdx.x;
  const int wave = t >> 6, lane = t & 63;
  const int wr = wave >> 1, wc = wave & 1;
  const int r0 = t >> 2, seg = t & 3;
  const int fr = lane & 15, fg = lane >> 4;
  const f16* pa0 = A + (long)r0 * lda + seg * 8;
  const f16* pa1 = A + (long)(r0 + 64) * lda + seg * 8;
  const f16* bfp = BF + (long)(wc * 4) * 512 + (long)lane * 8;

  f16x8 a0 = *(const f16x8*)(pa0);
  f16x8 a1 = *(const f16x8*)(pa1);

  #pragma unroll 1
  for (int kt = 0; kt < kIters; ++kt) {
    __syncthreads();
    *(f16x8*)(As + r0 * 40 + seg * 8) = a0;
    *(f16x8*)(As + (r0 + 64) * 40 + seg * 8) = a1;
    __syncthreads();
    f16x8 bf[4];
    #pragma unroll
    for (int n = 0; n < 4; ++n)
      bf[n] = *(const f16x8*)(bfp + (long)(kt * 8 + n) * 512);
    if (kt + 1 < kIters) {
      const int kb = (kt + 1) * 32;
      a0 = *(const f16x8*)(pa0 + kb);
      a1 = *(const f16x8*)(pa1 + kb);
    }
    f16x8 af[4];
    #pragma unroll
    for (int m = 0; m < 4; ++m)
      af[m] = *(const f16x8*)(As + (wr * 64 + m * 16 + fr) * 40 + fg * 8);
    #pragma unroll
    for (int m = 0; m < 4; ++m)
      #pragma unroll
      for (int n = 0; n < 4; ++n)
        acc[m][n] = __builtin_amdgcn_mfma_f32_16x16x32_f16(af[m], bf[n], acc[m][n], 0, 0, 0);
  }
}

// ---------------------------------------------------------------------------
// QKV GEMM: A = wqF (fragged), B = x_h (staged).  grid dim3(8,131).
// ---------------------------------------------------------------------------
__global__ __launch_bounds__(256) void qkv_gemm(
    const f16* __restrict__ x_h, const f16* __restrict__ wqF,
    const float* __restrict__ bn_a, const float* __restrict__ bn_sh,
    f16* __restrict__ qb, f16* __restrict__ kb, f16* __restrict__ vt)
{
  __shared__ f16 Bs[128 * 40];
  const int id = blockIdx.x + blockIdx.y * 8;          // [0,1048)
  const int lin = (id & 7) * 131 + (id >> 3);          // bijective [0,1048)
  const int row0 = (lin & 7) * 128;                    // channel block
  const int col0 = (lin >> 3) * 128;                   // token block (banded)
  f32x4 acc[4][4];
  #pragma unroll
  for (int m = 0; m < 4; ++m)
    #pragma unroll
    for (int n = 0; n < 4; ++n) acc[m][n] = (f32x4){0.f, 0.f, 0.f, 0.f};
  gemm_coreA(wqF + (long)(lin & 7) * 65536, x_h + (long)col0 * 512,
             512, 16, 16703 - col0, Bs, acc);
  const int lane = threadIdx.x & 63, wave = threadIdx.x >> 6;
  const int wr = wave >> 1, wc = wave & 1, fr = lane & 15, fg = lane >> 4;
  #pragma unroll
  for (int m = 0; m < 4; ++m) {
    const int chBase = row0 + wr * 64 + m * 16 + fg * 4;   // channel quad
    const float4 ba4 = *(const float4*)(bn_a + chBase);
    const float4 bs4 = *(const float4*)(bn_sh + chBase);
    const int hh = chBase >> 7, r = chBase & 127;          // quad-uniform cat
    #pragma unroll
    for (int n = 0; n < 4; ++n) {
      int tok = col0 + wc * 64 + n * 16 + fr;
      if (tok < 16704) {
        int bi = tok / 1044;
        int ni = tok - bi * 1044;
        long bh = (long)(bi * 8 + hh);
        float v0 = acc[m][n][0] * ba4.x + bs4.x;
        float v1 = acc[m][n][1] * ba4.y + bs4.y;
        float v2 = acc[m][n][2] * ba4.z + bs4.z;
        float v3 = acc[m][n][3] * ba4.w + bs4.w;
        if (r < 32) {
          f16x4 pk = {(f16)(v0 * QSCALE), (f16)(v1 * QSCALE),
                      (f16)(v2 * QSCALE), (f16)(v3 * QSCALE)};
          *(f16x4*)(qb + (bh * 1152 + ni) * 32 + r) = pk;
        } else if (r < 64) {
          f16x4 pk = {(f16)v0, (f16)v1, (f16)v2, (f16)v3};
          *(f16x4*)(kb + (bh * 1088 + ni) * 32 + (r - 32)) = pk;
        } else {
          f16* vp = vt + (bh * 64 + (r - 64)) * 1088 + ni;
          vp[0]        = (f16)v0;
          vp[1088]     = (f16)v1;
          vp[2 * 1088] = (f16)v2;
          vp[3 * 1088] = (f16)v3;
        }
      }
    }
  }
}

// ---------------------------------------------------------------------------
// depthwise conv branch (verbatim)
// ---------------------------------------------------------------------------
__global__ __launch_bounds__(256) void conv_kernel(
    const f16* __restrict__ vt, const float* __restrict__ conv_w,
    const float* __restrict__ conv_b, f16* __restrict__ vcT)
{
  __shared__ f16 img[16][34][36];
  const int b = blockIdx.y, g = blockIdx.x;
  const int c0 = g * 16, h = c0 >> 6, ci0 = c0 & 63;
  const int t = threadIdx.x;
  for (int i = t; i < 16 * 34 * 36; i += 256) ((f16*)img)[i] = (f16)0.f;
  __syncthreads();
  const int d = t >> 2, seg = t & 3;
  const f16* src = vt + ((long)(b * 8 + h) * 64 + d) * 1088 + ci0 * 16 + seg * 64;
  const int dhib = d >> 5;
  const int s2 = d & 31;
  #pragma unroll
  for (int j = 0; j < 8; ++j) {
    f16x8 vv = *(const f16x8*)(src + j * 8);
    #pragma unroll
    for (int e = 0; e < 8; ++e) {
      int local = seg * 64 + j * 8 + e;
      int cl = local >> 4, rr = local & 15;
      float xv = (float)vv[e];
      float hs = xv * fminf(fmaxf(xv + 3.f, 0.f), 6.f) * (1.f / 6.f);
      img[cl][1 + rr * 2 + dhib][1 + s2] = (f16)hs;
    }
  }
  __syncthreads();
  const int cl = t & 15, pg = t >> 4;
  const int c = c0 + cl;
  float w[9];
  #pragma unroll
  for (int i = 0; i < 9; ++i) w[i] = conv_w[c * 9 + i];
  const float bias = conv_b[c];
  for (int i = 0; i < 64; ++i) {
    int p = pg + i * 16;
    int s1 = p >> 5, ss2 = p & 31;
    float a = bias;
    #pragma unroll
    for (int di = 0; di < 3; ++di)
      #pragma unroll
      for (int dj = 0; dj < 3; ++dj)
        a += w[di * 3 + dj] * (float)img[cl][s1 + di][ss2 + dj];
    vcT[((long)b * 1024 + p) * 512 + c] = (f16)a;
  }
}

// ---------------------------------------------------------------------------
// fused attention — ROUND-9 PROVEN VERSION (68 us) verbatim.
// k-tile=32, 4-wave shared double-buffered LDS, setprio on PV, grid (9,128).
// ---------------------------------------------------------------------------
__global__ __launch_bounds__(256, 4) void attn_kernel(
    const f16* __restrict__ qb, const f16* __restrict__ kb,
    const f16* __restrict__ vt, f16* __restrict__ opad)
{
  __shared__ f16 kls[2][4 * 32 * 8];   // 2 KB/buf
  __shared__ f16 vls[2][4 * 64 * 8];   // 4 KB/buf
  __shared__ float l_sh[4][32];

  const int id = blockIdx.x + blockIdx.y * 9;
  const int xcd = id & 7, sl = id >> 3;
  const int bh = xcd * 16 + sl / 9, qblk = sl % 9;
  const int b = bh >> 3, h = bh & 7;
  const int t = threadIdx.x;
  const int wave = t >> 6, lane = t & 63;
  const int lq = lane & 31, hi = lane >> 5;
  const int q0 = qblk * 128 + wave * 32;

  const f16* qb_ = qb + (long)bh * 1152 * 32;
  const f16* kb_ = kb + (long)bh * 1088 * 32;
  const f16* vt_ = vt + (long)bh * 64 * 1088;

  const f16x8 qf0 = *(const f16x8*)(qb_ + (long)(q0 + lq) * 32 + hi * 8);
  const f16x8 qf1 = *(const f16x8*)(qb_ + (long)(q0 + lq) * 32 + 16 + hi * 8);

  const int sk_k = t >> 3, sk_s8 = t & 7;
  const int sk_seg = sk_s8 >> 1, sk_half = sk_s8 & 1;
  const int sv_d = t >> 2, sv_p = t & 3;
  const int wkoff = (sk_seg * 32 + ((sk_k + sk_seg) & 31)) * 16 + sk_half * 8;
  const int wvoff = (sv_p * 64 + ((sv_d + sv_p) & 63)) * 16;
  int koff[2], voff[2][2];
  #pragma unroll
  for (int ss = 0; ss < 2; ++ss) {
    int ss2 = 2 * ss + hi;
    koff[ss] = (ss2 * 32 + ((lq + ss2) & 31)) * 16;
  }
  #pragma unroll
  for (int nd = 0; nd < 2; ++nd)
    #pragma unroll
    for (int ks = 0; ks < 2; ++ks) {
      int kk4 = 2 * ks + hi;
      voff[nd][ks] = (kk4 * 64 + ((nd * 32 + lq + kk4) & 63)) * 16;
    }

  f16x4 stk;
  f16x8 stv;
  auto load_tile = [&](int kt) {
    stk = *(const f16x4*)(kb_ + (long)(kt * 32 + sk_k) * 32 + sk_s8 * 4);
    stv = *(const f16x8*)(vt_ + (long)sv_d * 1088 + kt * 32 + sv_p * 8);
  };
  auto write_tile = [&](int buf) {
    *(f16x4*)((char*)kls[buf] + wkoff) = stk;
    *(f16x8*)((char*)vls[buf] + wvoff) = stv;
  };

  f32x16 o0 = zero16(), o1 = zero16();
  float lsum = 0.f;

  load_tile(0);
  write_tile(0);
  __syncthreads();

  int cur = 0;
  #pragma unroll 1
  for (int kt = 0; kt < 33; ++kt) {
    if (kt < 32) load_tile(kt + 1);
    const char* kcur = (const char*)kls[cur];
    const char* vcur = (const char*)vls[cur];
    f16x8 kf0 = *(const f16x8*)(kcur + koff[0]);
    f16x8 kf1 = *(const f16x8*)(kcur + koff[1]);
    f32x16 s = zero16();
    s = __builtin_amdgcn_mfma_f32_32x32x16_f16(kf0, qf0, s, 0, 0, 0);
    s = __builtin_amdgcn_mfma_f32_32x32x16_f16(kf1, qf1, s, 0, 0, 0);
    float p[16];
    #pragma unroll
    for (int r = 0; r < 16; ++r) p[r] = EXP2(s[r]);
    if (kt == 32) {
      #pragma unroll
      for (int r = 0; r < 16; ++r) {
        int cr = (r & 3) + 8 * (r >> 2) + 4 * hi;
        p[r] = (cr < 20) ? p[r] : 0.f;
      }
    }
    float t8[8];
    #pragma unroll
    for (int r = 0; r < 8; ++r) t8[r] = p[r] + p[r + 8];
    lsum += ((t8[0] + t8[1]) + (t8[2] + t8[3])) + ((t8[4] + t8[5]) + (t8[6] + t8[7]));
    f16x8 pa0, pa1;
    pack_block(p, pa0, pa1);
    __builtin_amdgcn_s_setprio(1);
    {
      f16x8 vf00 = *(const f16x8*)(vcur + voff[0][0]);
      f16x8 vf10 = *(const f16x8*)(vcur + voff[1][0]);
      o0 = __builtin_amdgcn_mfma_f32_32x32x16_f16(pa0, vf00, o0, 0, 0, 0);
      o1 = __builtin_amdgcn_mfma_f32_32x32x16_f16(pa0, vf10, o1, 0, 0, 0);
      f16x8 vf01 = *(const f16x8*)(vcur + voff[0][1]);
      f16x8 vf11 = *(const f16x8*)(vcur + voff[1][1]);
      o0 = __builtin_amdgcn_mfma_f32_32x32x16_f16(pa1, vf01, o0, 0, 0, 0);
      o1 = __builtin_amdgcn_mfma_f32_32x32x16_f16(pa1, vf11, o1, 0, 0, 0);
    }
    __builtin_amdgcn_s_setprio(0);
    if (kt < 32) write_tile(cur ^ 1);
    __syncthreads();
    cur ^= 1;
  }

  lsum += __shfl_xor(lsum, 32);
  l_sh[wave][lq] = lsum;
  __syncthreads();
  float invl[16];
  #pragma unroll
  for (int r = 0; r < 16; ++r) {
    int cr = (r & 3) + 8 * (r >> 2) + 4 * hi;
    invl[r] = __builtin_amdgcn_rcpf(l_sh[wave][cr]);
  }
  #pragma unroll
  for (int nd = 0; nd < 2; ++nd) {
    #pragma unroll
    for (int r = 0; r < 16; ++r) {
      int cr = (r & 3) + 8 * (r >> 2) + 4 * hi;
      int q = q0 + cr;
      if (q < 1044) {
        float val = (nd ? o1[r] : o0[r]) * invl[r];
        unsigned flat = (unsigned)q * 512u + (unsigned)h * 64u + (unsigned)(nd * 32 + lq);
        unsigned c = flat / 1044u;
        unsigned np = flat - c * 1044u;
        opad[((long)b * 512 + c) * 1056 + np] = (f16)val;
      }
    }
  }
}

// ---------------------------------------------------------------------------
// proj GEMM: A = pwF (fragged), B = opad (staged).  grid dim3(4,8,16)
// ---------------------------------------------------------------------------
__global__ __launch_bounds__(256) void proj_gemm(
    const f16* __restrict__ pwF, const f16* __restrict__ opad,
    const float* __restrict__ proj_b, const f16* __restrict__ vcT,
    f16* __restrict__ xoT)
{
  __shared__ f16 Bs[128 * 40];
  const int id = blockIdx.x + blockIdx.y * 4 + blockIdx.z * 32;  // [0,512)
  const int lin = (id & 7) * 64 + (id >> 3);                     // bijective
  const int b = lin >> 5;
  const int rc = lin & 31;
  const int row0 = (rc >> 2) * 128;  // m (image pixel)
  const int col0 = (rc & 3) * 128;   // c (channel)
  f32x4 acc[4][4];
  #pragma unroll
  for (int m = 0; m < 4; ++m)
    #pragma unroll
    for (int n = 0; n < 4; ++n) acc[m][n] = (f32x4){0.f, 0.f, 0.f, 0.f};
  gemm_coreA(pwF + (long)(rc >> 2) * 135168, opad + ((long)b * 512 + col0) * 1056,
             1056, 33, 1 << 30, Bs, acc);
  const int lane = threadIdx.x & 63, wave = threadIdx.x >> 6;
  const int wr = wave >> 1, wc = wave & 1, fr = lane & 15, fg = lane >> 4;
  #pragma unroll
  for (int m = 0; m < 4; ++m) {
    #pragma unroll
    for (int rr = 0; rr < 4; ++rr) {
      int mi = row0 + wr * 64 + m * 16 + fg * 4 + rr;
      float pb = proj_b[mi];
      #pragma unroll
      for (int n = 0; n < 4; ++n) {
        int c = col0 + wc * 64 + n * 16 + fr;
        long idx = ((long)b * 1024 + mi) * 512 + c;
        xoT[idx] = (f16)(acc[m][n][rr] + pb + (float)vcT[idx]);
      }
    }
  }
}

// ---------------------------------------------------------------------------
// out GEMM: A = xoT (staged), B = owF (fragged).  grid dim3(4,8,16)
// ---------------------------------------------------------------------------
__global__ __launch_bounds__(256) void out_gemm(
    const f16* __restrict__ xoT, const f16* __restrict__ owF,
    const float* __restrict__ out_b, float* __restrict__ out)
{
  __shared__ f16 As[128 * 40];
  const int id = blockIdx.x + blockIdx.y * 4 + blockIdx.z * 32;  // [0,512)
  const int lin = (id & 7) * 64 + (id >> 3);                     // bijective
  const int b = lin >> 5;
  const int rc = lin & 31;
  const int row0 = (rc >> 2) * 128;
  const int col0 = (rc & 3) * 128;
  f32x4 acc[4][4];
  #pragma unroll
  for (int m = 0; m < 4; ++m)
    #pragma unroll
    for (int n = 0; n < 4; ++n) acc[m][n] = (f32x4){0.f, 0.f, 0.f, 0.f};
  gemm_coreB(xoT + ((long)b * 1024 + row0) * 512, owF + (long)(rc & 3) * 65536,
             512, 16, As, acc);
  const int lane = threadIdx.x & 63, wave = threadIdx.x >> 6;
  const int wr = wave >> 1, wc = wave & 1, fr = lane & 15, fg = lane >> 4;
  float ob[4];
  #pragma unroll
  for (int n = 0; n < 4; ++n) ob[n] = out_b[col0 + wc * 64 + n * 16 + fr];
  #pragma unroll
  for (int m = 0; m < 4; ++m) {
    #pragma unroll
    for (int rr = 0; rr < 4; ++rr) {
      int mi = row0 + wr * 64 + m * 16 + fg * 4 + rr;
      #pragma unroll
      for (int n = 0; n < 4; ++n) {
        int co = col0 + wc * 64 + n * 16 + fr;
        out[((long)b * 1024 + mi) * 512 + co] = acc[m][n][rr] + ob[n];
      }
    }
  }
}

// ---------------------------------------------------------------------------
extern "C" void kernel_launch(void* const* d_in, const int* in_sizes, int n_in,
                              void* d_out, int out_size, void* d_ws, size_t ws_size,
                              hipStream_t stream) {
  const float* x      = (const float*)d_in[0];
  const float* qkv_w  = (const float*)d_in[1];
  const float* bn_g   = (const float*)d_in[2];
  const float* bn_b   = (const float*)d_in[3];
  const float* bn_m   = (const float*)d_in[4];
  const float* bn_v   = (const float*)d_in[5];
  const float* conv_w = (const float*)d_in[6];
  const float* conv_b = (const float*)d_in[7];
  const float* proj_w = (const float*)d_in[8];
  const float* proj_b = (const float*)d_in[9];
  const float* out_w  = (const float*)d_in[10];
  const float* out_b  = (const float*)d_in[11];
  float* out = (float*)d_out;

  char* ws = (char*)d_ws;
  f16*   x_h   = (f16*)(ws + OFF_XH);
  f16*   wqF   = (f16*)(ws + OFF_WQF);
  f16*   pwF   = (f16*)(ws + OFF_PWF);
  f16*   owF   = (f16*)(ws + OFF_OWF);
  float* bn_a  = (float*)(ws + OFF_BNA);
  float* bn_sh = (float*)(ws + OFF_BNB);
  f16*   qb    = (f16*)(ws + OFF_QB);
  f16*   kb    = (f16*)(ws + OFF_KB);
  f16*   vt    = (f16*)(ws + OFF_VT);
  f16*   opad  = (f16*)(ws + OFF_OPAD);
  f16*   vcT   = (f16*)(ws + OFF_VCT);
  f16*   xoT   = (f16*)(ws + OFF_XOT);

  prep_kernel<<<1024, 256, 0, stream>>>(x, qkv_w, bn_g, bn_b, bn_m, bn_v,
                                        proj_w, out_w, x_h, wqF, pwF, owF,
                                        bn_a, bn_sh, qb, kb, vt, opad);
  qkv_gemm<<<dim3(8, 131), 256, 0, stream>>>(x_h, wqF, bn_a, bn_sh, qb, kb, vt);
  conv_kernel<<<dim3(32, 16), 256, 0, stream>>>(vt, conv_w, conv_b, vcT);
  attn_kernel<<<dim3(9, 128), 256, 0, stream>>>(qb, kb, vt, opad);
  proj_gemm<<<dim3(4, 8, 16), 256, 0, stream>>>(pwF, opad, proj_b, vcT, xoT);
  out_gemm<<<dim3(4, 8, 16), 256, 0, stream>>>(xoT, owF, out_b, out);
}

// Round 13
// 171.891 us; speedup vs baseline: 1.1560x; 1.0711x over previous
//
#include <hip/hip_runtime.h>
#include <hip/hip_fp16.h>

typedef _Float16 f16;
typedef _Float16 f16x8 __attribute__((ext_vector_type(8)));
typedef _Float16 f16x4 __attribute__((ext_vector_type(4)));
typedef float    f32x4 __attribute__((ext_vector_type(4)));
typedef float    f32x16 __attribute__((ext_vector_type(16)));

#define DEV __device__ __forceinline__

DEV int imin(int a, int b) { return a < b ? a : b; }

#if defined(__has_builtin)
#  if __has_builtin(__builtin_amdgcn_exp2f)
#    define EXP2(x) __builtin_amdgcn_exp2f(x)
#  else
#    define EXP2(x) __expf((x) * 0.6931471805599453f)
#  endif
#else
#  define EXP2(x) __expf((x) * 0.6931471805599453f)
#endif

// q pre-scale: (1/sqrt(32)) * log2(e) so softmax is p = 2^s
#define QSCALE (0.17677669529663687f * 1.4426950408889634f)

// ---------------------------------------------------------------------------
// Problem constants: B=16, N=1044, DIM=512, H=8, KD=32, D=64
// q padded to 1152 rows, k/v to 1088, o cols to 1056
// ---------------------------------------------------------------------------

// workspace offsets (bytes) — round-3/6 proven layout (XH slot now unused)
constexpr size_t OFF_XH   = 0;            // (unused)
constexpr size_t OFF_WQ   = 17104896;     // qkv_w fp16 (1024,512)        1,048,576
constexpr size_t OFF_PW   = 18153472;     // proj_w fp16 (1024,1056)      2,162,688
constexpr size_t OFF_OW   = 20316160;     // out_w fp16 (512,512)           524,288
constexpr size_t OFF_BNA  = 20840448;     // bn scale fp32 (1024)
constexpr size_t OFF_BNB  = 20844544;     // bn shift fp32 (1024)
constexpr size_t OFF_QB   = 20848640;     // q fp16 (128,1152,32)         9,437,184
constexpr size_t OFF_KB   = 30285824;     // k fp16 (128,1088,32)         8,912,896
constexpr size_t OFF_VT   = 39198720;     // v^T fp16 (128,64,1088)      17,825,792
constexpr size_t OFF_OPAD = 57024512;     // o fp16 (16,512,1056)        17,301,504
constexpr size_t OFF_VCT  = 74326016;     // vcT fp16 (16,1024,512)      16,777,216
constexpr size_t OFF_XOT  = 91103232;     // xoT fp16 (16,1024,512)      16,777,216

DEV f32x16 zero16() {
  f32x16 z;
  #pragma unroll
  for (int i = 0; i < 16; ++i) z[i] = 0.f;
  return z;
}

DEV unsigned pk2(float a, float b) {
  auto h = __builtin_amdgcn_cvt_pkrtz(a, b);
  union { decltype(h) x; unsigned u; } t;
  t.x = h;
  return t.u;
}

DEV void plswap(unsigned &a, unsigned &b) {
  asm("v_permlane32_swap_b32 %0, %1" : "+v"(a), "+v"(b));
}

union W4 { unsigned w[4]; f16x8 v; };

DEV void pack_block(const float p[16], f16x8 &a0, f16x8 &a1) {
  unsigned w0 = pk2(p[0], p[1]),   w1 = pk2(p[2], p[3]);
  unsigned w2 = pk2(p[4], p[5]),   w3 = pk2(p[6], p[7]);
  unsigned w4 = pk2(p[8], p[9]),   w5 = pk2(p[10], p[11]);
  unsigned w6 = pk2(p[12], p[13]), w7 = pk2(p[14], p[15]);
  plswap(w0, w2); plswap(w1, w3);
  plswap(w4, w6); plswap(w5, w7);
  W4 u; u.w[0] = w0; u.w[1] = w1; u.w[2] = w2; u.w[3] = w3; a0 = u.v;
  W4 v; v.w[0] = w4; v.w[1] = w5; v.w[2] = w6; v.w[3] = w7; a1 = v.v;
}

// ---------------------------------------------------------------------------
// prep: weight fp16 conversions, BN fold, zero pads (x round-trip REMOVED)
// ---------------------------------------------------------------------------
__global__ __launch_bounds__(256) void prep_kernel(
    const float* __restrict__ qkv_w,
    const float* __restrict__ bn_g, const float* __restrict__ bn_b,
    const float* __restrict__ bn_m, const float* __restrict__ bn_v,
    const float* __restrict__ proj_w, const float* __restrict__ out_w,
    f16* __restrict__ wq_h, f16* __restrict__ pw_h, f16* __restrict__ ow_h,
    float* __restrict__ bn_a, float* __restrict__ bn_sh,
    f16* __restrict__ qb, f16* __restrict__ kb, f16* __restrict__ vt,
    f16* __restrict__ opad)
{
  long tid = (long)blockIdx.x * blockDim.x + threadIdx.x;
  long gsz = (long)gridDim.x * blockDim.x;

  for (long i = tid; i < 524288; i += gsz) wq_h[i] = (f16)qkv_w[i];
  for (long i = tid; i < 1081344; i += gsz) {
    long m = i / 1056, nn = i - m * 1056;
    pw_h[i] = (nn < 1044) ? (f16)proj_w[m * 1044 + nn] : (f16)0.f;
  }
  for (long i = tid; i < 262144; i += gsz) ow_h[i] = (f16)out_w[i];
  for (long i = tid; i < 1024; i += gsz) {
    float a = bn_g[i] * rsqrtf(bn_v[i] + 1e-5f);
    bn_a[i] = a;
    bn_sh[i] = bn_b[i] - bn_m[i] * a;
  }
  for (long i = tid; i < 13824; i += gsz) {
    int bh = (int)(i / 108);
    int nn = 1044 + (int)(i - (long)bh * 108);
    f16* q = qb + ((long)bh * 1152 + nn) * 32;
    for (int j = 0; j < 32; ++j) q[j] = (f16)0.f;
  }
  for (long i = tid; i < 5632; i += gsz) {
    int bh = (int)(i / 44);
    int nn = 1044 + (int)(i - (long)bh * 44);
    f16* k = kb + ((long)bh * 1088 + nn) * 32;
    for (int j = 0; j < 32; ++j) k[j] = (f16)0.f;
  }
  for (long i = tid; i < 8192; i += gsz) {
    f16* v = vt + i * 1088 + 1044;
    for (int j = 0; j < 44; ++j) v[j] = (f16)0.f;
  }
  for (long i = tid; i < 8192; i += gsz) {
    f16* o = opad + i * 1056 + 1044;
    for (int j = 0; j < 12; ++j) o[j] = (f16)0.f;
  }
}

// ---------------------------------------------------------------------------
// shared 128x128xK NT-GEMM core (r7/r9 proven: BK=32, LDS stride 40, single
// buffer, 2 barriers, T14 prefetch after barrier2; clamps on both sides)
// ---------------------------------------------------------------------------
DEV void gemm_core(const f16* __restrict__ A, const f16* __restrict__ B,
                   int lda, int ldb, int kIters, int rowClampA, int rowClampB,
                   f16* As, f16* Bs, f32x4 acc[4][4])
{
  const int t = threadIdx.x;
  const int wave = t >> 6, lane = t & 63;
  const int wr = wave >> 1, wc = wave & 1;
  const int r0 = t >> 2, seg = t & 3;
  const int fr = lane & 15, fg = lane >> 4;
  const int ra0 = imin(r0, rowClampA);
  const int ra1 = imin(r0 + 64, rowClampA);
  const int rb0 = imin(r0, rowClampB);
  const int rb1 = imin(r0 + 64, rowClampB);

  const f16* pa0 = A + (long)ra0 * lda + seg * 8;
  const f16* pa1 = A + (long)ra1 * lda + seg * 8;
  const f16* pb0 = B + (long)rb0 * ldb + seg * 8;
  const f16* pb1 = B + (long)rb1 * ldb + seg * 8;

  f16x8 a0, a1, b0, b1;
  a0 = *(const f16x8*)(pa0);
  a1 = *(const f16x8*)(pa1);
  b0 = *(const f16x8*)(pb0);
  b1 = *(const f16x8*)(pb1);

  #pragma unroll 1
  for (int kt = 0; kt < kIters; ++kt) {
    __syncthreads();
    *(f16x8*)(As + r0 * 40 + seg * 8) = a0;
    *(f16x8*)(As + (r0 + 64) * 40 + seg * 8) = a1;
    *(f16x8*)(Bs + r0 * 40 + seg * 8) = b0;
    *(f16x8*)(Bs + (r0 + 64) * 40 + seg * 8) = b1;
    __syncthreads();
    if (kt + 1 < kIters) {
      const int kb = (kt + 1) * 32;
      a0 = *(const f16x8*)(pa0 + kb);
      a1 = *(const f16x8*)(pa1 + kb);
      b0 = *(const f16x8*)(pb0 + kb);
      b1 = *(const f16x8*)(pb1 + kb);
    }
    f16x8 af[4], bf[4];
    #pragma unroll
    for (int m = 0; m < 4; ++m)
      af[m] = *(const f16x8*)(As + (wr * 64 + m * 16 + fr) * 40 + fg * 8);
    #pragma unroll
    for (int n = 0; n < 4; ++n)
      bf[n] = *(const f16x8*)(Bs + (wc * 64 + n * 16 + fr) * 40 + fg * 8);
    #pragma unroll
    for (int m = 0; m < 4; ++m)
      #pragma unroll
      for (int n = 0; n < 4; ++n)
        acc[m][n] = __builtin_amdgcn_mfma_f32_16x16x32_f16(af[m], bf[n], acc[m][n], 0, 0, 0);
  }
}

// ---------------------------------------------------------------------------
// variant: B side is FP32 (x read directly from HBM), converted in-reg
// during staging; identical LDS layout/pipeline.
// ---------------------------------------------------------------------------
DEV void gemm_core_xf32(const f16* __restrict__ A, const float* __restrict__ B,
                        int lda, int ldb, int kIters, int rowClampB,
                        f16* As, f16* Bs, f32x4 acc[4][4])
{
  const int t = threadIdx.x;
  const int wave = t >> 6, lane = t & 63;
  const int wr = wave >> 1, wc = wave & 1;
  const int r0 = t >> 2, seg = t & 3;
  const int fr = lane & 15, fg = lane >> 4;
  const int rb0 = imin(r0, rowClampB);
  const int rb1 = imin(r0 + 64, rowClampB);

  const f16*   pa0 = A + (long)r0 * lda + seg * 8;
  const f16*   pa1 = A + (long)(r0 + 64) * lda + seg * 8;
  const float* pb0 = B + (long)rb0 * ldb + seg * 8;
  const float* pb1 = B + (long)rb1 * ldb + seg * 8;

  f16x8 a0, a1;
  float4 b0l, b0h, b1l, b1h;
  auto cvt8 = [](float4 lo, float4 hi) -> f16x8 {
    f16x8 r;
    r[0] = (f16)lo.x; r[1] = (f16)lo.y; r[2] = (f16)lo.z; r[3] = (f16)lo.w;
    r[4] = (f16)hi.x; r[5] = (f16)hi.y; r[6] = (f16)hi.z; r[7] = (f16)hi.w;
    return r;
  };
  a0 = *(const f16x8*)(pa0);
  a1 = *(const f16x8*)(pa1);
  b0l = ((const float4*)pb0)[0]; b0h = ((const float4*)pb0)[1];
  b1l = ((const float4*)pb1)[0]; b1h = ((const float4*)pb1)[1];

  #pragma unroll 1
  for (int kt = 0; kt < kIters; ++kt) {
    __syncthreads();
    *(f16x8*)(As + r0 * 40 + seg * 8) = a0;
    *(f16x8*)(As + (r0 + 64) * 40 + seg * 8) = a1;
    *(f16x8*)(Bs + r0 * 40 + seg * 8) = cvt8(b0l, b0h);
    *(f16x8*)(Bs + (r0 + 64) * 40 + seg * 8) = cvt8(b1l, b1h);
    __syncthreads();
    if (kt + 1 < kIters) {
      const int kb = (kt + 1) * 32;
      a0 = *(const f16x8*)(pa0 + kb);
      a1 = *(const f16x8*)(pa1 + kb);
      b0l = ((const float4*)(pb0 + kb))[0]; b0h = ((const float4*)(pb0 + kb))[1];
      b1l = ((const float4*)(pb1 + kb))[0]; b1h = ((const float4*)(pb1 + kb))[1];
    }
    f16x8 af[4], bf[4];
    #pragma unroll
    for (int m = 0; m < 4; ++m)
      af[m] = *(const f16x8*)(As + (wr * 64 + m * 16 + fr) * 40 + fg * 8);
    #pragma unroll
    for (int n = 0; n < 4; ++n)
      bf[n] = *(const f16x8*)(Bs + (wc * 64 + n * 16 + fr) * 40 + fg * 8);
    #pragma unroll
    for (int m = 0; m < 4; ++m)
      #pragma unroll
      for (int n = 0; n < 4; ++n)
        acc[m][n] = __builtin_amdgcn_mfma_f32_16x16x32_f16(af[m], bf[n], acc[m][n], 0, 0, 0);
  }
}

// ---------------------------------------------------------------------------
// QKV GEMM, transposed: A = wq_h (f16), B = x (FP32 direct).  grid (8,131)
// ---------------------------------------------------------------------------
__global__ __launch_bounds__(256) void qkv_gemm(
    const float* __restrict__ x, const f16* __restrict__ wq,
    const float* __restrict__ bn_a, const float* __restrict__ bn_sh,
    f16* __restrict__ qb, f16* __restrict__ kb, f16* __restrict__ vt)
{
  __shared__ f16 As[128 * 40];
  __shared__ f16 Bs[128 * 40];
  const int id = blockIdx.x + blockIdx.y * 8;          // [0,1048)
  const int lin = (id & 7) * 131 + (id >> 3);          // bijective [0,1048)
  const int row0 = (lin & 7) * 128;                    // channel block
  const int col0 = (lin >> 3) * 128;                   // token block (banded)
  f32x4 acc[4][4];
  #pragma unroll
  for (int m = 0; m < 4; ++m)
    #pragma unroll
    for (int n = 0; n < 4; ++n) acc[m][n] = (f32x4){0.f, 0.f, 0.f, 0.f};
  gemm_core_xf32(wq + (long)row0 * 512, x + (long)col0 * 512, 512, 512, 16,
                 16703 - col0, As, Bs, acc);
  const int lane = threadIdx.x & 63, wave = threadIdx.x >> 6;
  const int wr = wave >> 1, wc = wave & 1, fr = lane & 15, fg = lane >> 4;
  #pragma unroll
  for (int m = 0; m < 4; ++m) {
    const int chBase = row0 + wr * 64 + m * 16 + fg * 4;   // channel quad
    const float4 ba4 = *(const float4*)(bn_a + chBase);
    const float4 bs4 = *(const float4*)(bn_sh + chBase);
    const int hh = chBase >> 7, r = chBase & 127;          // quad-uniform cat
    #pragma unroll
    for (int n = 0; n < 4; ++n) {
      int tok = col0 + wc * 64 + n * 16 + fr;
      if (tok < 16704) {
        int bi = tok / 1044;
        int ni = tok - bi * 1044;
        long bh = (long)(bi * 8 + hh);
        float v0 = acc[m][n][0] * ba4.x + bs4.x;
        float v1 = acc[m][n][1] * ba4.y + bs4.y;
        float v2 = acc[m][n][2] * ba4.z + bs4.z;
        float v3 = acc[m][n][3] * ba4.w + bs4.w;
        if (r < 32) {
          f16x4 pk = {(f16)(v0 * QSCALE), (f16)(v1 * QSCALE),
                      (f16)(v2 * QSCALE), (f16)(v3 * QSCALE)};
          *(f16x4*)(qb + (bh * 1152 + ni) * 32 + r) = pk;
        } else if (r < 64) {
          f16x4 pk = {(f16)v0, (f16)v1, (f16)v2, (f16)v3};
          *(f16x4*)(kb + (bh * 1088 + ni) * 32 + (r - 32)) = pk;
        } else {
          f16* vp = vt + (bh * 64 + (r - 64)) * 1088 + ni;
          vp[0]        = (f16)v0;
          vp[1088]     = (f16)v1;
          vp[2 * 1088] = (f16)v2;
          vp[3 * 1088] = (f16)v3;
        }
      }
    }
  }
}

// ---------------------------------------------------------------------------
// depthwise conv branch (verbatim)
// ---------------------------------------------------------------------------
__global__ __launch_bounds__(256) void conv_kernel(
    const f16* __restrict__ vt, const float* __restrict__ conv_w,
    const float* __restrict__ conv_b, f16* __restrict__ vcT)
{
  __shared__ f16 img[16][34][36];
  const int b = blockIdx.y, g = blockIdx.x;
  const int c0 = g * 16, h = c0 >> 6, ci0 = c0 & 63;
  const int t = threadIdx.x;
  for (int i = t; i < 16 * 34 * 36; i += 256) ((f16*)img)[i] = (f16)0.f;
  __syncthreads();
  const int d = t >> 2, seg = t & 3;
  const f16* src = vt + ((long)(b * 8 + h) * 64 + d) * 1088 + ci0 * 16 + seg * 64;
  const int dhib = d >> 5;
  const int s2 = d & 31;
  #pragma unroll
  for (int j = 0; j < 8; ++j) {
    f16x8 vv = *(const f16x8*)(src + j * 8);
    #pragma unroll
    for (int e = 0; e < 8; ++e) {
      int local = seg * 64 + j * 8 + e;
      int cl = local >> 4, rr = local & 15;
      float xv = (float)vv[e];
      float hs = xv * fminf(fmaxf(xv + 3.f, 0.f), 6.f) * (1.f / 6.f);
      img[cl][1 + rr * 2 + dhib][1 + s2] = (f16)hs;
    }
  }
  __syncthreads();
  const int cl = t & 15, pg = t >> 4;
  const int c = c0 + cl;
  float w[9];
  #pragma unroll
  for (int i = 0; i < 9; ++i) w[i] = conv_w[c * 9 + i];
  const float bias = conv_b[c];
  for (int i = 0; i < 64; ++i) {
    int p = pg + i * 16;
    int s1 = p >> 5, ss2 = p & 31;
    float a = bias;
    #pragma unroll
    for (int di = 0; di < 3; ++di)
      #pragma unroll
      for (int dj = 0; dj < 3; ++dj)
        a += w[di * 3 + dj] * (float)img[cl][s1 + di][ss2 + dj];
    vcT[((long)b * 1024 + p) * 512 + c] = (f16)a;
  }
}

// ---------------------------------------------------------------------------
// fused attention — r9-proven (66-68 us) verbatim.  k-tile=32, 4 waves,
// shared double-buffered LDS, setprio on PV.  grid (9,128), XCD-grouped.
// ---------------------------------------------------------------------------
__global__ __launch_bounds__(256, 4) void attn_kernel(
    const f16* __restrict__ qb, const f16* __restrict__ kb,
    const f16* __restrict__ vt, f16* __restrict__ opad)
{
  __shared__ f16 kls[2][4 * 32 * 8];   // 2 KB/buf
  __shared__ f16 vls[2][4 * 64 * 8];   // 4 KB/buf
  __shared__ float l_sh[4][32];

  const int id = blockIdx.x + blockIdx.y * 9;
  const int xcd = id & 7, sl = id >> 3;
  const int bh = xcd * 16 + sl / 9, qblk = sl % 9;
  const int b = bh >> 3, h = bh & 7;
  const int t = threadIdx.x;
  const int wave = t >> 6, lane = t & 63;
  const int lq = lane & 31, hi = lane >> 5;
  const int q0 = qblk * 128 + wave * 32;

  const f16* qb_ = qb + (long)bh * 1152 * 32;
  const f16* kb_ = kb + (long)bh * 1088 * 32;
  const f16* vt_ = vt + (long)bh * 64 * 1088;

  const f16x8 qf0 = *(const f16x8*)(qb_ + (long)(q0 + lq) * 32 + hi * 8);
  const f16x8 qf1 = *(const f16x8*)(qb_ + (long)(q0 + lq) * 32 + 16 + hi * 8);

  const int sk_k = t >> 3, sk_s8 = t & 7;
  const int sk_seg = sk_s8 >> 1, sk_half = sk_s8 & 1;
  const int sv_d = t >> 2, sv_p = t & 3;
  const int wkoff = (sk_seg * 32 + ((sk_k + sk_seg) & 31)) * 16 + sk_half * 8;
  const int wvoff = (sv_p * 64 + ((sv_d + sv_p) & 63)) * 16;
  int koff[2], voff[2][2];
  #pragma unroll
  for (int ss = 0; ss < 2; ++ss) {
    int ss2 = 2 * ss + hi;
    koff[ss] = (ss2 * 32 + ((lq + ss2) & 31)) * 16;
  }
  #pragma unroll
  for (int nd = 0; nd < 2; ++nd)
    #pragma unroll
    for (int ks = 0; ks < 2; ++ks) {
      int kk4 = 2 * ks + hi;
      voff[nd][ks] = (kk4 * 64 + ((nd * 32 + lq + kk4) & 63)) * 16;
    }

  f16x4 stk;
  f16x8 stv;
  auto load_tile = [&](int kt) {
    stk = *(const f16x4*)(kb_ + (long)(kt * 32 + sk_k) * 32 + sk_s8 * 4);
    stv = *(const f16x8*)(vt_ + (long)sv_d * 1088 + kt * 32 + sv_p * 8);
  };
  auto write_tile = [&](int buf) {
    *(f16x4*)((char*)kls[buf] + wkoff) = stk;
    *(f16x8*)((char*)vls[buf] + wvoff) = stv;
  };

  f32x16 o0 = zero16(), o1 = zero16();
  float lsum = 0.f;

  load_tile(0);
  write_tile(0);
  __syncthreads();

  int cur = 0;
  #pragma unroll 1
  for (int kt = 0; kt < 33; ++kt) {
    if (kt < 32) load_tile(kt + 1);
    const char* kcur = (const char*)kls[cur];
    const char* vcur = (const char*)vls[cur];
    f16x8 kf0 = *(const f16x8*)(kcur + koff[0]);
    f16x8 kf1 = *(const f16x8*)(kcur + koff[1]);
    f32x16 s = zero16();
    s = __builtin_amdgcn_mfma_f32_32x32x16_f16(kf0, qf0, s, 0, 0, 0);
    s = __builtin_amdgcn_mfma_f32_32x32x16_f16(kf1, qf1, s, 0, 0, 0);
    float p[16];
    #pragma unroll
    for (int r = 0; r < 16; ++r) p[r] = EXP2(s[r]);
    if (kt == 32) {
      #pragma unroll
      for (int r = 0; r < 16; ++r) {
        int cr = (r & 3) + 8 * (r >> 2) + 4 * hi;
        p[r] = (cr < 20) ? p[r] : 0.f;
      }
    }
    float t8[8];
    #pragma unroll
    for (int r = 0; r < 8; ++r) t8[r] = p[r] + p[r + 8];
    lsum += ((t8[0] + t8[1]) + (t8[2] + t8[3])) + ((t8[4] + t8[5]) + (t8[6] + t8[7]));
    f16x8 pa0, pa1;
    pack_block(p, pa0, pa1);
    __builtin_amdgcn_s_setprio(1);
    {
      f16x8 vf00 = *(const f16x8*)(vcur + voff[0][0]);
      f16x8 vf10 = *(const f16x8*)(vcur + voff[1][0]);
      o0 = __builtin_amdgcn_mfma_f32_32x32x16_f16(pa0, vf00, o0, 0, 0, 0);
      o1 = __builtin_amdgcn_mfma_f32_32x32x16_f16(pa0, vf10, o1, 0, 0, 0);
      f16x8 vf01 = *(const f16x8*)(vcur + voff[0][1]);
      f16x8 vf11 = *(const f16x8*)(vcur + voff[1][1]);
      o0 = __builtin_amdgcn_mfma_f32_32x32x16_f16(pa1, vf01, o0, 0, 0, 0);
      o1 = __builtin_amdgcn_mfma_f32_32x32x16_f16(pa1, vf11, o1, 0, 0, 0);
    }
    __builtin_amdgcn_s_setprio(0);
    if (kt < 32) write_tile(cur ^ 1);
    __syncthreads();
    cur ^= 1;
  }

  lsum += __shfl_xor(lsum, 32);
  l_sh[wave][lq] = lsum;
  __syncthreads();
  float invl[16];
  #pragma unroll
  for (int r = 0; r < 16; ++r) {
    int cr = (r & 3) + 8 * (r >> 2) + 4 * hi;
    invl[r] = __builtin_amdgcn_rcpf(l_sh[wave][cr]);
  }
  #pragma unroll
  for (int nd = 0; nd < 2; ++nd) {
    #pragma unroll
    for (int r = 0; r < 16; ++r) {
      int cr = (r & 3) + 8 * (r >> 2) + 4 * hi;
      int q = q0 + cr;
      if (q < 1044) {
        float val = (nd ? o1[r] : o0[r]) * invl[r];
        unsigned flat = (unsigned)q * 512u + (unsigned)h * 64u + (unsigned)(nd * 32 + lq);
        unsigned c = flat / 1044u;
        unsigned np = flat - c * 1044u;
        opad[((long)b * 512 + c) * 1056 + np] = (f16)val;
      }
    }
  }
}

// ---------------------------------------------------------------------------
// proj GEMM (r9 verbatim).  grid dim3(4,8,16)
// ---------------------------------------------------------------------------
__global__ __launch_bounds__(256) void proj_gemm(
    const f16* __restrict__ pw, const f16* __restrict__ opad,
    const float* __restrict__ proj_b, const f16* __restrict__ vcT,
    f16* __restrict__ xoT)
{
  __shared__ f16 As[128 * 40];
  __shared__ f16 Bs[128 * 40];
  const int id = blockIdx.x + blockIdx.y * 4 + blockIdx.z * 32;  // [0,512)
  const int lin = (id & 7) * 64 + (id >> 3);                     // bijective
  const int b = lin >> 5;
  const int rc = lin & 31;
  const int row0 = (rc >> 2) * 128;  // m (image pixel)
  const int col0 = (rc & 3) * 128;   // c (channel)
  f32x4 acc[4][4];
  #pragma unroll
  for (int m = 0; m < 4; ++m)
    #pragma unroll
    for (int n = 0; n < 4; ++n) acc[m][n] = (f32x4){0.f, 0.f, 0.f, 0.f};
  gemm_core(pw + (long)row0 * 1056, opad + ((long)b * 512 + col0) * 1056,
            1056, 1056, 33, 1 << 30, 1 << 30, As, Bs, acc);
  const int lane = threadIdx.x & 63, wave = threadIdx.x >> 6;
  const int wr = wave >> 1, wc = wave & 1, fr = lane & 15, fg = lane >> 4;
  #pragma unroll
  for (int m = 0; m < 4; ++m) {
    #pragma unroll
    for (int rr = 0; rr < 4; ++rr) {
      int mi = row0 + wr * 64 + m * 16 + fg * 4 + rr;
      float pb = proj_b[mi];
      #pragma unroll
      for (int n = 0; n < 4; ++n) {
        int c = col0 + wc * 64 + n * 16 + fr;
        long idx = ((long)b * 1024 + mi) * 512 + c;
        xoT[idx] = (f16)(acc[m][n][rr] + pb + (float)vcT[idx]);
      }
    }
  }
}

// ---------------------------------------------------------------------------
// out GEMM (r9 verbatim).  grid dim3(4,8,16)
// ---------------------------------------------------------------------------
__global__ __launch_bounds__(256) void out_gemm(
    const f16* __restrict__ xoT, const f16* __restrict__ ow,
    const float* __restrict__ out_b, float* __restrict__ out)
{
  __shared__ f16 As[128 * 40];
  __shared__ f16 Bs[128 * 40];
  const int id = blockIdx.x + blockIdx.y * 4 + blockIdx.z * 32;  // [0,512)
  const int lin = (id & 7) * 64 + (id >> 3);                     // bijective
  const int b = lin >> 5;
  const int rc = lin & 31;
  const int row0 = (rc >> 2) * 128;
  const int col0 = (rc & 3) * 128;
  f32x4 acc[4][4];
  #pragma unroll
  for (int m = 0; m < 4; ++m)
    #pragma unroll
    for (int n = 0; n < 4; ++n) acc[m][n] = (f32x4){0.f, 0.f, 0.f, 0.f};
  gemm_core(xoT + ((long)b * 1024 + row0) * 512, ow + (long)col0 * 512,
            512, 512, 16, 1 << 30, 1 << 30, As, Bs, acc);
  const int lane = threadIdx.x & 63, wave = threadIdx.x >> 6;
  const int wr = wave >> 1, wc = wave & 1, fr = lane & 15, fg = lane >> 4;
  float ob[4];
  #pragma unroll
  for (int n = 0; n < 4; ++n) ob[n] = out_b[col0 + wc * 64 + n * 16 + fr];
  #pragma unroll
  for (int m = 0; m < 4; ++m) {
    #pragma unroll
    for (int rr = 0; rr < 4; ++rr) {
      int mi = row0 + wr * 64 + m * 16 + fg * 4 + rr;
      #pragma unroll
      for (int n = 0; n < 4; ++n) {
        int co = col0 + wc * 64 + n * 16 + fr;
        out[((long)b * 1024 + mi) * 512 + co] = acc[m][n][rr] + ob[n];
      }
    }
  }
}

// ---------------------------------------------------------------------------
extern "C" void kernel_launch(void* const* d_in, const int* in_sizes, int n_in,
                              void* d_out, int out_size, void* d_ws, size_t ws_size,
                              hipStream_t stream) {
  const float* x      = (const float*)d_in[0];
  const float* qkv_w  = (const float*)d_in[1];
  const float* bn_g   = (const float*)d_in[2];
  const float* bn_b   = (const float*)d_in[3];
  const float* bn_m   = (const float*)d_in[4];
  const float* bn_v   = (const float*)d_in[5];
  const float* conv_w = (const float*)d_in[6];
  const float* conv_b = (const float*)d_in[7];
  const float* proj_w = (const float*)d_in[8];
  const float* proj_b = (const float*)d_in[9];
  const float* out_w  = (const float*)d_in[10];
  const float* out_b  = (const float*)d_in[11];
  float* out = (float*)d_out;

  char* ws = (char*)d_ws;
  f16*   wq_h  = (f16*)(ws + OFF_WQ);
  f16*   pw_h  = (f16*)(ws + OFF_PW);
  f16*   ow_h  = (f16*)(ws + OFF_OW);
  float* bn_a  = (float*)(ws + OFF_BNA);
  float* bn_sh = (float*)(ws + OFF_BNB);
  f16*   qb    = (f16*)(ws + OFF_QB);
  f16*   kb    = (f16*)(ws + OFF_KB);
  f16*   vt    = (f16*)(ws + OFF_VT);
  f16*   opad  = (f16*)(ws + OFF_OPAD);
  f16*   vcT   = (f16*)(ws + OFF_VCT);
  f16*   xoT   = (f16*)(ws + OFF_XOT);

  prep_kernel<<<1024, 256, 0, stream>>>(qkv_w, bn_g, bn_b, bn_m, bn_v,
                                        proj_w, out_w, wq_h, pw_h, ow_h,
                                        bn_a, bn_sh, qb, kb, vt, opad);
  qkv_gemm<<<dim3(8, 131), 256, 0, stream>>>(x, wq_h, bn_a, bn_sh, qb, kb, vt);
  conv_kernel<<<dim3(32, 16), 256, 0, stream>>>(vt, conv_w, conv_b, vcT);
  attn_kernel<<<dim3(9, 128), 256, 0, stream>>>(qb, kb, vt, opad);
  proj_gemm<<<dim3(4, 8, 16), 256, 0, stream>>>(pw_h, opad, proj_b, vcT, xoT);
  out_gemm<<<dim3(4, 8, 16), 256, 0, stream>>>(xoT, ow_h, out_b, out);
}